// Round 1
// baseline (4392.300 us; speedup 1.0000x reference)
//
#include <hip/hip_runtime.h>
#include <math.h>

#define B 64
#define TF 64
#define TE 32
#define E_DIM 40
#define H 100
#define H2 200
#define H3 300
#define SP 256
#define EV 20000
#define ROWS (B*TF)        // 4096
#define NCOLS 456          // 200 score cols + 256 Y cols

// ---------------- setup: W_KC[k][c] = rows of (att_W1 bottom | sp1_W enc-part), plus v, c2 ----
__global__ __launch_bounds__(256) void k_setup(const float* att_W1, const float* sp1_W,
        const float* sp2_W, const float* sp2_b, float* W_KC, float* v, float* c2) {
  int bid = blockIdx.x;
  if (bid < 179) {
    int idx = bid*256 + threadIdx.x;
    if (idx < 100*NCOLS) {
      int k = idx / NCOLS, c = idx - k*NCOLS;
      float val;
      if (c < H2) val = att_W1[(100+k)*H2 + c];
      else        val = sp1_W[(200+k)*SP + (c-200)];
      W_KC[idx] = val;                      // W_KC[k*456 + c]
    }
  } else if (bid == 179) {
    int k = threadIdx.x;                    // 0..255
    float s = 0.f;
    for (int j = 0; j < SP; ++j) s += sp2_W[k*SP + j];
    v[k] = s * (1.f/256.f);
  } else {
    if (threadIdx.x == 0) {
      float s = 0.f;
      for (int j = 0; j < SP; ++j) s += sp2_b[j];
      *c2 = s * (1.f/256.f);
    }
  }
}

// ---------------- encoder xs = embed @ enc_W + enc_b[0] (parallel over all (b,t)) ----
__global__ __launch_bounds__(320) void k_embed(const int* enc_in, const float* femb,
        const float* enc_W, const float* enc_b, float* xs_all) {
  int row = blockIdx.x;
  int j = threadIdx.x;
  __shared__ __align__(16) float emb[E_DIM];
  int tok = enc_in[row];
  if (j < E_DIM) emb[j] = femb[tok*E_DIM + j];
  __syncthreads();
  if (j < H3) {
    float acc = enc_b[j];                   // b[0]
    #pragma unroll
    for (int k = 0; k < E_DIM; ++k) acc += emb[k]*enc_W[k*H3 + j];
    xs_all[row*H3 + j] = acc;
  }
}

// ---------------- encoder GRU recurrence: one block per batch, U register-resident ----
__global__ __launch_bounds__(192) void k_enc(const float* __restrict__ enc_U,
        const float* __restrict__ enc_b, const float* __restrict__ xs_all,
        float* __restrict__ enc_T, float* __restrict__ h_state) {
  int b = blockIdx.x, t = threadIdx.x;
  __shared__ __align__(16) float hsh[104];
  __shared__ __align__(16) float hs[304];

  float2 Ur[100];
  float2 bias = {0.f, 0.f};
  if (t < 150) {
    const float* base = enc_U + 2*t;
    #pragma unroll
    for (int k = 0; k < 100; ++k) Ur[k] = *(const float2*)(base + k*H3);
    bias = *(const float2*)(enc_b + H3 + 2*t);
  }
  if (t < H) hsh[t] = 0.f;
  __syncthreads();

  #pragma unroll 1
  for (int step = 0; step < TF; ++step) {
    int row = b*TF + step;
    float xz = 0.f, xr = 0.f, xh = 0.f;
    if (t < H) {
      xz = xs_all[row*H3 + t];
      xr = xs_all[row*H3 + 100 + t];
      xh = xs_all[row*H3 + 200 + t];
    }
    if (t < 150) {
      float a0 = bias.x, a1 = bias.y;
      const float4* h4 = (const float4*)hsh;
      #pragma unroll
      for (int k4 = 0; k4 < 25; ++k4) {
        float4 hv = h4[k4];
        a0 += hv.x*Ur[k4*4+0].x + hv.y*Ur[k4*4+1].x + hv.z*Ur[k4*4+2].x + hv.w*Ur[k4*4+3].x;
        a1 += hv.x*Ur[k4*4+0].y + hv.y*Ur[k4*4+1].y + hv.z*Ur[k4*4+2].y + hv.w*Ur[k4*4+3].y;
      }
      hs[2*t]   = a0;
      hs[2*t+1] = a1;
    }
    __syncthreads();
    if (t < H) {
      float z = 1.f/(1.f+expf(-(xz + hs[t])));
      float r = 1.f/(1.f+expf(-(xr + hs[100+t])));
      float cand = tanhf(xh + r*hs[200+t]);
      float hn = z*hsh[t] + (1.f-z)*cand;
      hsh[t] = hn;
      enc_T[t*ROWS + row] = hn;
    }
    __syncthreads();
  }
  if (t < H) h_state[b*H + t] = hsh[t];
}

// ---------------- one-time P init: P[b,t,c] = enc[b,t,:] @ W_KC[:,c] ----
__global__ __launch_bounds__(512) void k_initP(const float* __restrict__ enc_T,
        const float* __restrict__ W_KC, float* __restrict__ P_g) {
  int tg = blockIdx.x, b = blockIdx.y;
  int tid = threadIdx.x;
  __shared__ float es[100*16];
  for (int idx = tid; idx < 1600; idx += 512) {
    int k = idx >> 4, tt = idx & 15;
    es[idx] = enc_T[k*ROWS + b*TF + tg*16 + tt];
  }
  __syncthreads();
  for (int idx = tid; idx < 16*NCOLS; idx += 512) {
    int t = idx / NCOLS, c = idx - t*NCOLS;
    float a = 0.f;
    #pragma unroll
    for (int k4 = 0; k4 < 25; ++k4) {
      int k = k4*4;
      a += es[(k+0)*16+t]*W_KC[(k+0)*NCOLS+c] + es[(k+1)*16+t]*W_KC[(k+1)*NCOLS+c]
         + es[(k+2)*16+t]*W_KC[(k+2)*NCOLS+c] + es[(k+3)*16+t]*W_KC[(k+3)*NCOLS+c];
    }
    P_g[(b*TF + tg*16 + t)*NCOLS + c] = a;
  }
}

// ---------------- persistent decoder: 1 block/batch, all 32 steps, P+enc in LDS ----
__global__ __launch_bounds__(1024) void k_dec(
    const float* __restrict__ P_g, const float* __restrict__ enc_T,
    const float* __restrict__ h_state,
    const float* __restrict__ dec_W, const float* __restrict__ dec_U,
    const float* __restrict__ dec_b,
    const float* __restrict__ sp1_W, const float* __restrict__ sp1_b,
    const float* __restrict__ att_W1, const float* __restrict__ att_W2,
    const float* __restrict__ W_KC,
    const float* __restrict__ v, const float* __restrict__ c2p,
    float* __restrict__ dec_out) {
  int b = blockIdx.x, tid = threadIdx.x;
  int w = tid >> 6, lane = tid & 63;

  __shared__ float P[64*NCOLS];          // 116736 B  — P[t*456 + c]
  __shared__ float encs[6400];           // 25600 B   — encs[k*64 + t]
  __shared__ __align__(16) float rd[104];
  __shared__ __align__(16) float h[104];
  __shared__ __align__(16) float xs[304];
  __shared__ __align__(16) float hs[304];
  __shared__ float ccp[2][256];
  __shared__ float hW[200], q[200];
  __shared__ float Rsh[NCOLS];
  __shared__ float vsh[256];
  __shared__ float scores[64], alpha[64], gg[64];

  // ---- init: load state into LDS ----
  for (int idx = tid; idx < 64*NCOLS; idx += 1024)
    P[idx] = P_g[b*64*NCOLS + idx];
  for (int idx = tid; idx < 6400; idx += 1024)
    encs[idx] = enc_T[(idx >> 6)*ROWS + b*TF + (idx & 63)];
  if (tid < H) h[tid] = h_state[b*H + tid];
  if (tid < 256) vsh[tid] = v[tid];
  float c2 = *c2p;
  __syncthreads();
  // initial hW = h@att_W1_top, q = h@att_W2
  if (tid < 400) {
    int col = (tid < H2) ? tid : tid - H2;
    const float* Wm = (tid < H2) ? att_W1 : att_W2;
    float a = 0.f;
    for (int k = 0; k < H; ++k) a += h[k]*Wm[k*H2 + col];
    if (tid < H2) hW[col] = a; else q[col] = a;
  }
  __syncthreads();

  for (int s = 0; s < TE; ++s) {
    // phase 1: scores_t = sum_c tanh(hW_c + P[t,c]) * q_c   (wave w -> t = w*4+i)
    #pragma unroll
    for (int i = 0; i < 4; ++i) {
      int t = w*4 + i;
      float sp = 0.f;
      for (int c = lane; c < H2; c += 64)
        sp += tanhf(hW[c] + P[t*NCOLS + c]) * q[c];
      #pragma unroll
      for (int mk = 32; mk >= 1; mk >>= 1) sp += __shfl_xor(sp, mk);
      if (lane == 0) scores[t] = sp;
    }
    __syncthreads();
    // phase 2: softmax over t (wave 0)
    if (w == 0) {
      float sc = scores[lane];
      float m = sc;
      #pragma unroll
      for (int mk = 32; mk >= 1; mk >>= 1) m = fmaxf(m, __shfl_xor(m, mk));
      float ex = expf(sc - m);
      float ssum = ex;
      #pragma unroll
      for (int mk = 32; mk >= 1; mk >>= 1) ssum += __shfl_xor(ssum, mk);
      alpha[lane] = ex / ssum;
    }
    __syncthreads();
    // phase 3: attentive read rd_j = sum_t alpha_t * enc[t,j]
    {
      float al = alpha[lane];
      for (int j = w; j < H; j += 16) {
        float vs = al * encs[j*64 + lane];
        #pragma unroll
        for (int mk = 32; mk >= 1; mk >>= 1) vs += __shfl_xor(vs, mk);
        if (lane == 0) rd[j] = vs;
      }
    }
    __syncthreads();
    // phase 4: xs = rd@dec_W+b0 (0..299) | hs = h@dec_U+b1 (512..811) | R = rd@W_KC (rest)
    if (tid < H3) {
      int j = tid;
      float a = dec_b[j];
      const float4* r4 = (const float4*)rd;
      #pragma unroll
      for (int k4 = 0; k4 < 25; ++k4) {
        float4 rv = r4[k4]; int k = k4*4;
        a += rv.x*dec_W[(k+0)*H3+j] + rv.y*dec_W[(k+1)*H3+j]
           + rv.z*dec_W[(k+2)*H3+j] + rv.w*dec_W[(k+3)*H3+j];
      }
      xs[j] = a;
    } else if (tid >= 512 && tid < 512 + H3) {
      int j = tid - 512;
      float a = dec_b[H3 + j];
      const float4* h4 = (const float4*)h;
      #pragma unroll
      for (int k4 = 0; k4 < 25; ++k4) {
        float4 hv = h4[k4]; int k = k4*4;
        a += hv.x*dec_U[(k+0)*H3+j] + hv.y*dec_U[(k+1)*H3+j]
           + hv.z*dec_U[(k+2)*H3+j] + hv.w*dec_U[(k+3)*H3+j];
      }
      hs[j] = a;
    } else {
      int ridx = (tid < 512) ? (tid - 300) : (tid - 600);   // [0,212) U [212,424)
      for (int c = ridx; c < NCOLS; c += 424) {
        float a = 0.f;
        const float4* r4 = (const float4*)rd;
        #pragma unroll
        for (int k4 = 0; k4 < 25; ++k4) {
          float4 rv = r4[k4]; int k = k4*4;
          a += rv.x*W_KC[(k+0)*NCOLS+c] + rv.y*W_KC[(k+1)*NCOLS+c]
             + rv.z*W_KC[(k+2)*NCOLS+c] + rv.w*W_KC[(k+3)*NCOLS+c];
        }
        Rsh[c] = a;
      }
    }
    __syncthreads();
    // phase 5: GRU gate update -> h (new)
    if (tid < H) {
      float z = 1.f/(1.f+expf(-(xs[tid] + hs[tid])));
      float r = 1.f/(1.f+expf(-(xs[100+tid] + hs[100+tid])));
      float cand = tanhf(xs[200+tid] + r*hs[200+tid]);
      float hn = z*h[tid] + (1.f-z)*cand;
      h[tid] = hn;
      dec_out[(b*TE + s)*H + tid] = hn;
    }
    __syncthreads();
    // phase 6: cc partials (0..511) | next-step hW/q from new h (512..911)
    if (tid < 512) {
      int jj = tid & 255, kh = tid >> 8;
      const float* inv = kh ? rd : h;
      const float* wb = sp1_W + kh*100*SP;
      float a = kh ? 0.f : sp1_b[jj];
      const float4* i4 = (const float4*)inv;
      #pragma unroll
      for (int k4 = 0; k4 < 25; ++k4) {
        float4 iv = i4[k4]; int k = k4*4;
        a += iv.x*wb[(k+0)*SP+jj] + iv.y*wb[(k+1)*SP+jj]
           + iv.z*wb[(k+2)*SP+jj] + iv.w*wb[(k+3)*SP+jj];
      }
      ccp[kh][jj] = a;
    } else if (tid < 912) {
      int c = tid - 512;
      int col = (c < H2) ? c : c - H2;
      const float* Wm = (c < H2) ? att_W1 : att_W2;
      float a = 0.f;
      const float4* h4 = (const float4*)h;
      #pragma unroll
      for (int k4 = 0; k4 < 25; ++k4) {
        float4 hv = h4[k4]; int k = k4*4;
        a += hv.x*Wm[(k+0)*H2+col] + hv.y*Wm[(k+1)*H2+col]
           + hv.z*Wm[(k+2)*H2+col] + hv.w*Wm[(k+3)*H2+col];
      }
      if (c < H2) hW[col] = a; else q[col] = a;
    }
    __syncthreads();
    // phase 7: gate g_t = sigmoid( sum_j relu(cc_j + P[t,200+j]) * v_j + c2 )
    #pragma unroll
    for (int i = 0; i < 4; ++i) {
      int t = w*4 + i;
      float gp = 0.f;
      #pragma unroll
      for (int jj = 0; jj < 4; ++jj) {
        int j = lane + jj*64;
        float y = ccp[0][j] + ccp[1][j] + P[t*NCOLS + H2 + j];
        gp += fmaxf(y, 0.f) * vsh[j];
      }
      #pragma unroll
      for (int mk = 32; mk >= 1; mk >>= 1) gp += __shfl_xor(gp, mk);
      if (lane == 0) gg[t] = 1.f/(1.f+expf(-(gp + c2)));
    }
    __syncthreads();
    // phase 8: incremental blend  P = g*P + (1-g)*R ;  enc = g*enc + (1-g)*rd
    #pragma unroll
    for (int i = 0; i < 4; ++i) {
      int t = w*4 + i;
      float gt = gg[t], om = 1.f - gt;
      for (int c = lane; c < NCOLS; c += 64)
        P[t*NCOLS + c] = gt*P[t*NCOLS + c] + om*Rsh[c];
    }
    for (int idx = tid; idx < 6400; idx += 1024) {
      int k = idx >> 6, t = idx & 63;
      float gt = gg[t];
      encs[idx] = gt*encs[idx] + (1.f - gt)*rd[k];
    }
    __syncthreads();
  }
}

// ---------------- ff1: hid = relu(dec_out @ ff1_W + b) ----
__global__ __launch_bounds__(128) void k_ff1(const float* dec_out, const float* ff1_W,
        const float* ff1_b, float* hid) {
  int row = blockIdx.x, j = threadIdx.x;
  __shared__ __align__(16) float a[104];
  if (j < H) a[j] = dec_out[row*H + j];
  __syncthreads();
  if (j < H) {
    float acc = ff1_b[j];
    const float4* a4 = (const float4*)a;
    #pragma unroll
    for (int k4 = 0; k4 < 25; ++k4) {
      float4 av = a4[k4];
      int k = k4*4;
      acc += av.x*ff1_W[(k+0)*H+j] + av.y*ff1_W[(k+1)*H+j] + av.z*ff1_W[(k+2)*H+j] + av.w*ff1_W[(k+3)*H+j];
    }
    hid[row*H + j] = fmaxf(acc, 0.f);
  }
}

// ---------------- logits GEMM: [2048,100] x [100,20000] -> d_out ----
#define KC 20
__global__ __launch_bounds__(256) void k_logits(const float* hid, const float* ff2_W,
        const float* ff2_b, float* out) {
  int bx = blockIdx.x, by = blockIdx.y;
  int tid = threadIdx.x;
  int tx = tid & 15, ty = tid >> 4;
  __shared__ __align__(16) float At[100*132];
  __shared__ __align__(16) float Wt[KC*132];
  int r0 = by*128;
  int c0 = bx*128;
  for (int i = tid; i < 128*100; i += 256) {
    int r = i & 127, k = i >> 7;
    At[k*132 + r] = hid[(r0+r)*H + k];
  }
  float acc[8][8];
  #pragma unroll
  for (int i = 0; i < 8; ++i) {
    #pragma unroll
    for (int j = 0; j < 8; ++j) acc[i][j] = 0.f;
  }
  for (int kc = 0; kc < 100; kc += KC) {
    __syncthreads();
    for (int i = tid; i < 128*KC; i += 256) {
      int cidx = i & 127, kk = i >> 7;
      int gc = c0 + cidx;
      Wt[kk*132 + cidx] = (gc < EV) ? ff2_W[(size_t)(kc+kk)*EV + gc] : 0.f;
    }
    __syncthreads();
    #pragma unroll
    for (int kk = 0; kk < KC; ++kk) {
      const float* Ar = At + (kc+kk)*132;
      const float* Wr = Wt + kk*132;
      float4 a0 = *(const float4*)(Ar + ty*4);
      float4 a1 = *(const float4*)(Ar + 64 + ty*4);
      float4 w0 = *(const float4*)(Wr + tx*4);
      float4 w1 = *(const float4*)(Wr + 64 + tx*4);
      float av[8] = {a0.x,a0.y,a0.z,a0.w,a1.x,a1.y,a1.z,a1.w};
      float wv[8] = {w0.x,w0.y,w0.z,w0.w,w1.x,w1.y,w1.z,w1.w};
      #pragma unroll
      for (int i = 0; i < 8; ++i) {
        #pragma unroll
        for (int j = 0; j < 8; ++j) acc[i][j] += av[i]*wv[j];
      }
    }
  }
  #pragma unroll
  for (int i = 0; i < 8; ++i) {
    int r = r0 + ty*4 + (i < 4 ? i : 60 + i);
    float* orow = out + (size_t)r*EV;
    int ca = c0 + tx*4;
    if (ca < EV) {
      float4 bb = *(const float4*)(ff2_b + ca);
      float4 val = {acc[i][0]+bb.x, acc[i][1]+bb.y, acc[i][2]+bb.z, acc[i][3]+bb.w};
      *(float4*)(orow + ca) = val;
    }
    int cb = c0 + 64 + tx*4;
    if (cb < EV) {
      float4 bb = *(const float4*)(ff2_b + cb);
      float4 val = {acc[i][4]+bb.x, acc[i][5]+bb.y, acc[i][6]+bb.z, acc[i][7]+bb.w};
      *(float4*)(orow + cb) = val;
    }
  }
}

// ---------------- in-place row softmax on d_out ----
__global__ __launch_bounds__(256) void k_softmax(float* out) {
  int row = blockIdx.x, tid = threadIdx.x;
  float* p = out + (size_t)row*EV;
  float m = -1e30f, ssum = 0.f;
  for (int j = tid; j < EV; j += 256) {
    float x = p[j];
    if (x > m) { ssum = ssum*expf(m - x) + 1.f; m = x; }
    else ssum += expf(x - m);
  }
  __shared__ float sm[256], ss[256];
  sm[tid] = m; ss[tid] = ssum;
  __syncthreads();
  for (int st = 128; st >= 1; st >>= 1) {
    if (tid < st) {
      float m2 = sm[tid+st], s2 = ss[tid+st];
      float M = fmaxf(sm[tid], m2);
      ss[tid] = ss[tid]*expf(sm[tid]-M) + s2*expf(m2-M);
      sm[tid] = M;
    }
    __syncthreads();
  }
  float M = sm[0];
  float inv = 1.f/ss[0];
  for (int j = tid; j < EV; j += 256) {
    p[j] = expf(p[j] - M) * inv;
  }
}

extern "C" void kernel_launch(void* const* d_in, const int* in_sizes, int n_in,
                              void* d_out, int out_size, void* d_ws, size_t ws_size,
                              hipStream_t stream) {
  (void)in_sizes; (void)n_in; (void)out_size;
  const int*   enc_in  = (const int*)d_in[0];
  const float* femb    = (const float*)d_in[2];
  const float* enc_W   = (const float*)d_in[4];
  const float* enc_U   = (const float*)d_in[5];
  const float* enc_b   = (const float*)d_in[6];
  const float* dec_W   = (const float*)d_in[7];
  const float* dec_U   = (const float*)d_in[8];
  const float* dec_b   = (const float*)d_in[9];
  const float* att_W1  = (const float*)d_in[10];
  const float* att_W2  = (const float*)d_in[11];
  const float* sp1_W   = (const float*)d_in[12];
  const float* sp1_b   = (const float*)d_in[13];
  const float* sp2_W   = (const float*)d_in[14];
  const float* sp2_b   = (const float*)d_in[15];
  const float* ff1_W   = (const float*)d_in[16];
  const float* ff1_b   = (const float*)d_in[17];
  const float* ff2_W   = (const float*)d_in[18];
  const float* ff2_b   = (const float*)d_in[19];
  float* out = (float*)d_out;
  float* ws  = (float*)d_ws;

  float* enc_T  = ws + 0;          // 100*4096  = 409600
  float* W_KC   = ws + 409600;     // 100*456   = 45600
  float* h_st   = ws + 455200;     // 64*100    = 6400
  float* dec_o  = ws + 461600;     // 2048*100  = 204800
  float* hid    = ws + 666400;     // 2048*100  = 204800
  float* vbuf   = ws + 871200;     // 256
  float* c2buf  = ws + 871456;     // 4 (pad)
  float* xs_all = ws + 871460;     // 4096*300  = 1228800 (dead after k_enc)
  float* P_g    = ws + 871460;     // 4096*456  = 1867776 (aliases xs_all)
  if (ws_size < (size_t)2739236*4) return;   // need ~11.0 MB

  k_setup<<<181, 256, 0, stream>>>(att_W1, sp1_W, sp2_W, sp2_b, W_KC, vbuf, c2buf);
  k_embed<<<4096, 320, 0, stream>>>(enc_in, femb, enc_W, enc_b, xs_all);
  k_enc<<<64, 192, 0, stream>>>(enc_U, enc_b, xs_all, enc_T, h_st);
  k_initP<<<dim3(4, 64), 512, 0, stream>>>(enc_T, W_KC, P_g);
  k_dec<<<64, 1024, 0, stream>>>(P_g, enc_T, h_st, dec_W, dec_U, dec_b,
                                 sp1_W, sp1_b, att_W1, att_W2, W_KC,
                                 vbuf, c2buf, dec_o);
  k_ff1<<<2048, 128, 0, stream>>>(dec_o, ff1_W, ff1_b, hid);
  k_logits<<<dim3(157, 16), 256, 0, stream>>>(hid, ff2_W, ff2_b, out);
  k_softmax<<<2048, 256, 0, stream>>>(out);
}

// Round 2
// 2790.164 us; speedup vs baseline: 1.5742x; 1.5742x over previous
//
#include <hip/hip_runtime.h>
#include <math.h>

#define B 64
#define TF 64
#define TE 32
#define E_DIM 40
#define H 100
#define H2 200
#define H3 300
#define SP 256
#define EV 20000
#define ROWS (B*TF)        // 4096
#define NCOLS 456          // 200 score cols + 256 Y cols

// ---------------- setup: W_KC[k][c] = rows of (att_W1 bottom | sp1_W enc-part), plus v, c2 ----
__global__ __launch_bounds__(256) void k_setup(const float* att_W1, const float* sp1_W,
        const float* sp2_W, const float* sp2_b, float* W_KC, float* v, float* c2) {
  int bid = blockIdx.x;
  if (bid < 179) {
    int idx = bid*256 + threadIdx.x;
    if (idx < 100*NCOLS) {
      int k = idx / NCOLS, c = idx - k*NCOLS;
      float val;
      if (c < H2) val = att_W1[(100+k)*H2 + c];
      else        val = sp1_W[(200+k)*SP + (c-200)];
      W_KC[idx] = val;                      // W_KC[k*456 + c]
    }
  } else if (bid == 179) {
    int k = threadIdx.x;                    // 0..255
    float s = 0.f;
    for (int j = 0; j < SP; ++j) s += sp2_W[k*SP + j];
    v[k] = s * (1.f/256.f);
  } else {
    if (threadIdx.x == 0) {
      float s = 0.f;
      for (int j = 0; j < SP; ++j) s += sp2_b[j];
      *c2 = s * (1.f/256.f);
    }
  }
}

// ---------------- encoder xs = embed @ enc_W + enc_b[0] ----
__global__ __launch_bounds__(320) void k_embed(const int* enc_in, const float* femb,
        const float* enc_W, const float* enc_b, float* xs_all) {
  int row = blockIdx.x;
  int j = threadIdx.x;
  __shared__ __align__(16) float emb[E_DIM];
  int tok = enc_in[row];
  if (j < E_DIM) emb[j] = femb[tok*E_DIM + j];
  __syncthreads();
  if (j < H3) {
    float acc = enc_b[j];
    #pragma unroll
    for (int k = 0; k < E_DIM; ++k) acc += emb[k]*enc_W[k*H3 + j];
    xs_all[row*H3 + j] = acc;
  }
}

// ---------------- encoder GRU recurrence ----
__global__ __launch_bounds__(192) void k_enc(const float* __restrict__ enc_U,
        const float* __restrict__ enc_b, const float* __restrict__ xs_all,
        float* __restrict__ enc_T, float* __restrict__ h_state) {
  int b = blockIdx.x, t = threadIdx.x;
  __shared__ __align__(16) float hsh[104];
  __shared__ __align__(16) float hs[304];

  float2 Ur[100];
  float2 bias = {0.f, 0.f};
  if (t < 150) {
    const float* base = enc_U + 2*t;
    #pragma unroll
    for (int k = 0; k < 100; ++k) Ur[k] = *(const float2*)(base + k*H3);
    bias = *(const float2*)(enc_b + H3 + 2*t);
  }
  if (t < H) hsh[t] = 0.f;
  __syncthreads();

  #pragma unroll 1
  for (int step = 0; step < TF; ++step) {
    int row = b*TF + step;
    float xz = 0.f, xr = 0.f, xh = 0.f;
    if (t < H) {
      xz = xs_all[row*H3 + t];
      xr = xs_all[row*H3 + 100 + t];
      xh = xs_all[row*H3 + 200 + t];
    }
    if (t < 150) {
      float a0 = bias.x, a1 = bias.y;
      const float4* h4 = (const float4*)hsh;
      #pragma unroll
      for (int k4 = 0; k4 < 25; ++k4) {
        float4 hv = h4[k4];
        a0 += hv.x*Ur[k4*4+0].x + hv.y*Ur[k4*4+1].x + hv.z*Ur[k4*4+2].x + hv.w*Ur[k4*4+3].x;
        a1 += hv.x*Ur[k4*4+0].y + hv.y*Ur[k4*4+1].y + hv.z*Ur[k4*4+2].y + hv.w*Ur[k4*4+3].y;
      }
      hs[2*t]   = a0;
      hs[2*t+1] = a1;
    }
    __syncthreads();
    if (t < H) {
      float z = 1.f/(1.f+expf(-(xz + hs[t])));
      float r = 1.f/(1.f+expf(-(xr + hs[100+t])));
      float cand = tanhf(xh + r*hs[200+t]);
      float hn = z*hsh[t] + (1.f-z)*cand;
      hsh[t] = hn;
      enc_T[t*ROWS + row] = hn;
    }
    __syncthreads();
  }
  if (t < H) h_state[b*H + t] = hsh[t];
}

// ---------------- one-time P init: P[b,t,c] = enc[b,t,:] @ W_KC[:,c] ----
__global__ __launch_bounds__(512) void k_initP(const float* __restrict__ enc_T,
        const float* __restrict__ W_KC, float* __restrict__ P_g) {
  int tg = blockIdx.x, b = blockIdx.y;
  int tid = threadIdx.x;
  __shared__ float es[100*16];
  for (int idx = tid; idx < 1600; idx += 512) {
    int k = idx >> 4, tt = idx & 15;
    es[idx] = enc_T[k*ROWS + b*TF + tg*16 + tt];
  }
  __syncthreads();
  for (int idx = tid; idx < 16*NCOLS; idx += 512) {
    int t = idx / NCOLS, c = idx - t*NCOLS;
    float a = 0.f;
    #pragma unroll
    for (int k4 = 0; k4 < 25; ++k4) {
      int k = k4*4;
      a += es[(k+0)*16+t]*W_KC[(k+0)*NCOLS+c] + es[(k+1)*16+t]*W_KC[(k+1)*NCOLS+c]
         + es[(k+2)*16+t]*W_KC[(k+2)*NCOLS+c] + es[(k+3)*16+t]*W_KC[(k+3)*NCOLS+c];
    }
    P_g[(b*TF + tg*16 + t)*NCOLS + c] = a;
  }
}

// ---------------- initial hW = h@att_W1_top, q = h@att_W2 ----
__global__ __launch_bounds__(256) void k_init_att(const float* h_state, const float* att_W1,
        const float* att_W2, float* hW, float* q) {
  int b = blockIdx.x, c = threadIdx.x;
  __shared__ __align__(16) float h[104];
  if (c < H) h[c] = h_state[b*H + c];
  __syncthreads();
  if (c < H2) {
    float a1 = 0.f, a2 = 0.f;
    const float4* h4 = (const float4*)h;
    #pragma unroll
    for (int k4 = 0; k4 < 25; ++k4) {
      float4 hv = h4[k4];
      int k = k4*4;
      a1 += hv.x*att_W1[(k+0)*H2+c] + hv.y*att_W1[(k+1)*H2+c] + hv.z*att_W1[(k+2)*H2+c] + hv.w*att_W1[(k+3)*H2+c];
      a2 += hv.x*att_W2[(k+0)*H2+c] + hv.y*att_W2[(k+1)*H2+c] + hv.z*att_W2[(k+2)*H2+c] + hv.w*att_W2[(k+3)*H2+c];
    }
    hW[b*H2 + c] = a1;
    q[b*H2 + c]  = a2;
  }
}

// ---------------- D1 (per batch): lazy P/E update with g(s-1), scores, softmax, read ----
__global__ __launch_bounds__(512) void k_D1(int s,
    float* __restrict__ P_g, float* __restrict__ enc_T,
    const float* __restrict__ cc_g, const float* __restrict__ OUT,
    float* __restrict__ rd_g,
    const float* __restrict__ hW_g, const float* __restrict__ q_g,
    const float* __restrict__ v_g, const float* __restrict__ c2p) {
  int b = blockIdx.x, tid = threadIdx.x;
  int w = tid >> 6, lane = tid & 63;
  __shared__ float Ysub[64*260];      // 66560 B: stash of P Y-part (pre-update)
  __shared__ float Scd[64*204];       // 52224 B: stash of updated P score-part
  __shared__ float Esh[6400];         // 25600 B: updated enc [k][t]
  __shared__ float hWs[200], qs[200];
  __shared__ float ccs[256], Rsh[456], rdp[100], vsh[256];
  __shared__ float gsh[64], alpha[64], scores[64];

  float* Pb = P_g + (size_t)b*29184;
  if (tid < 200) { hWs[tid] = hW_g[b*H2+tid]; qs[tid] = q_g[b*H2+tid]; }
  if (tid < 256) { vsh[tid] = v_g[tid]; ccs[tid] = (s>0) ? cc_g[b*256+tid] : 0.f; }
  if (tid < 100) rdp[tid] = (s>0) ? rd_g[b*100+tid] : 0.f;
  for (int c = tid; c < 456; c += 512) Rsh[c] = (s>0) ? OUT[b*1056 + 600 + c] : 0.f;
  float c2 = *c2p;
  __syncthreads();

  if (s > 0) {
    // phase A: gate g_t from cc + P Y-part (pre-update); stash Y-part
    #pragma unroll
    for (int i = 0; i < 8; ++i) {
      int t = w*8 + i;
      float gp = 0.f;
      #pragma unroll
      for (int jj = 0; jj < 4; ++jj) {
        int j = lane + jj*64;
        float pv = Pb[t*456 + 200 + j];
        Ysub[t*260 + j] = pv;
        gp += fmaxf(ccs[j] + pv, 0.f) * vsh[j];
      }
      #pragma unroll
      for (int mk = 32; mk >= 1; mk >>= 1) gp += __shfl_xor(gp, mk);
      if (lane == 0) gsh[t] = 1.f/(1.f+expf(-(gp + c2)));
    }
    __syncthreads();
    // phase B: P = g*P + (1-g)*R (write back + stash score-part); E likewise
    #pragma unroll 2
    for (int idx = tid; idx < 29184; idx += 512) {
      int t = idx / 456, c = idx - t*456;
      float gt = gsh[t];
      float oldv = (c < 200) ? Pb[idx] : Ysub[t*260 + (c-200)];
      float nv = gt*oldv + (1.f-gt)*Rsh[c];
      Pb[idx] = nv;
      if (c < 200) Scd[t*204 + c] = nv;
    }
    #pragma unroll 2
    for (int idx = tid; idx < 6400; idx += 512) {
      int k = idx >> 6, t = idx & 63;
      float gt = gsh[t];
      float ev = enc_T[k*ROWS + b*TF + t];
      float nv = gt*ev + (1.f-gt)*rdp[k];
      Esh[idx] = nv;
      enc_T[k*ROWS + b*TF + t] = nv;
    }
  } else {
    for (int idx = tid; idx < 6400; idx += 512)
      Esh[idx] = enc_T[(idx>>6)*ROWS + b*TF + (idx&63)];
  }
  __syncthreads();

  // phase C: scores_t = sum_c tanh(hW_c + P[t,c]) q_c
  #pragma unroll
  for (int i = 0; i < 8; ++i) {
    int t = w*8 + i;
    float sp = 0.f;
    #pragma unroll
    for (int jj = 0; jj < 4; ++jj) {
      int c = lane + jj*64;
      if (c < 200) {
        float pv = (s > 0) ? Scd[t*204 + c] : Pb[t*456 + c];
        sp += tanhf(hWs[c] + pv) * qs[c];
      }
    }
    #pragma unroll
    for (int mk = 32; mk >= 1; mk >>= 1) sp += __shfl_xor(sp, mk);
    if (lane == 0) scores[t] = sp;
  }
  __syncthreads();
  // phase D: softmax over 64 t (wave 0)
  if (w == 0) {
    float sc = scores[lane];
    float m = sc;
    #pragma unroll
    for (int mk = 32; mk >= 1; mk >>= 1) m = fmaxf(m, __shfl_xor(m, mk));
    float ex = expf(sc - m);
    float ssum = ex;
    #pragma unroll
    for (int mk = 32; mk >= 1; mk >>= 1) ssum += __shfl_xor(ssum, mk);
    alpha[lane] = ex / ssum;
  }
  __syncthreads();
  // phase E: rd_j = sum_t alpha_t E[t,j]
  float al = alpha[lane];
  #pragma unroll
  for (int i = 0; i < 13; ++i) {
    int j = w + i*8;
    if (j < H) {
      float vs = al * Esh[j*64 + lane];
      #pragma unroll
      for (int mk = 32; mk >= 1; mk >>= 1) vs += __shfl_xor(vs, mk);
      if (lane == 0) rd_g[b*100 + j] = vs;
    }
  }
}

// ---------------- D2 (col-parallel): xs = rd@dec_W+b0 | hs = h@dec_U+b1 | R = rd@W_KC ----
// weights hoisted to registers: each weight column read exactly once per step.
__global__ __launch_bounds__(256) void k_D2(const float* __restrict__ rd_g,
    const float* __restrict__ h_cur, const float* __restrict__ dec_W,
    const float* __restrict__ dec_U, const float* __restrict__ W_KC,
    const float* __restrict__ dec_b, float* __restrict__ OUT) {
  int blk = blockIdx.x, tid = threadIdx.x;
  int bq = tid >> 6, lane = tid & 63;
  int seg, c0, ncols;
  if (blk < 5)       { seg = 0; c0 = blk*64;      ncols = 300; }
  else if (blk < 10) { seg = 1; c0 = (blk-5)*64;  ncols = 300; }
  else               { seg = 2; c0 = (blk-10)*64; ncols = 456; }
  int cg = c0 + lane;
  bool act = cg < ncols;
  int cgl = act ? cg : (ncols-1);

  __shared__ __align__(16) float inLDS[64*104];
  const float* src = (seg == 1) ? h_cur : rd_g;
  for (int i = tid; i < 6400; i += 256) {
    int bb = i / 100, k = i - bb*100;
    inLDS[bb*104 + k] = src[bb*100 + k];
  }
  const float* wp = (seg == 0) ? dec_W : (seg == 1) ? dec_U : W_KC;
  int ld = (seg == 2) ? 456 : 300;
  float4 wreg[25];
  #pragma unroll
  for (int k4 = 0; k4 < 25; ++k4) {
    wreg[k4].x = wp[(k4*4+0)*ld + cgl];
    wreg[k4].y = wp[(k4*4+1)*ld + cgl];
    wreg[k4].z = wp[(k4*4+2)*ld + cgl];
    wreg[k4].w = wp[(k4*4+3)*ld + cgl];
  }
  float bias0 = 0.f;
  if (seg == 0) bias0 = dec_b[cgl];
  else if (seg == 1) bias0 = dec_b[300 + cgl];
  int outc = (seg == 0) ? cg : (seg == 1) ? 300 + cg : 600 + cg;
  __syncthreads();
  #pragma unroll 1
  for (int i = 0; i < 16; ++i) {
    int bb = bq*16 + i;
    float acc = bias0;
    const float4* in4 = (const float4*)&inLDS[bb*104];
    #pragma unroll
    for (int k4 = 0; k4 < 25; ++k4) {
      float4 iv = in4[k4];
      acc += iv.x*wreg[k4].x + iv.y*wreg[k4].y + iv.z*wreg[k4].z + iv.w*wreg[k4].w;
    }
    if (act) OUT[bb*1056 + outc] = acc;
  }
}

// ---------------- D3: h_new (redundant pointwise) + cc | hW' | q' GEMMs ----
__global__ __launch_bounds__(512) void k_D3(int s,
    const float* __restrict__ OUT, const float* __restrict__ rd_g,
    const float* __restrict__ h_cur, float* __restrict__ h_nxt,
    const float* __restrict__ sp1_W, const float* __restrict__ sp1_b,
    const float* __restrict__ att_W1, const float* __restrict__ att_W2,
    float* __restrict__ cc_g, float* __restrict__ hW_g, float* __restrict__ q_g,
    float* __restrict__ dec_o) {
  int blk = blockIdx.x, tid = threadIdx.x;
  __shared__ __align__(16) float cat[64*208];   // [b][0:100]=h_new, [100:200]=rd
  __shared__ float psum[64*2*64];               // cc k-split partials

  for (int i = tid; i < 6400; i += 512) {
    int bb = i / 100, j = i - bb*100;
    const float* ob = OUT + bb*1056;
    float xz = ob[j], xr = ob[100+j], xh = ob[200+j];
    float hz = ob[300+j], hr = ob[400+j], hh = ob[500+j];
    float hv = h_cur[bb*100+j];
    float z = 1.f/(1.f+expf(-(xz+hz)));
    float r = 1.f/(1.f+expf(-(xr+hr)));
    float cand = tanhf(xh + r*hh);
    float hn = z*hv + (1.f-z)*cand;
    cat[bb*208 + j] = hn;
    cat[bb*208 + 100 + j] = rd_g[bb*100+j];
    if (blk == 0) { h_nxt[bb*100+j] = hn; dec_o[(bb*TE + s)*H + j] = hn; }
  }
  __syncthreads();

  if (blk < 4) {
    // cc: 64 cols per block, k-split-2 over the 200-long dot
    int c = tid & 63, half = (tid >> 6) & 1, bq = tid >> 7;   // bq 0..3
    int cg = blk*64 + c;
    int k0 = half*100;
    float4 wreg[25];
    #pragma unroll
    for (int k4 = 0; k4 < 25; ++k4) {
      int k = k0 + k4*4;
      wreg[k4].x = sp1_W[(k+0)*SP + cg];
      wreg[k4].y = sp1_W[(k+1)*SP + cg];
      wreg[k4].z = sp1_W[(k+2)*SP + cg];
      wreg[k4].w = sp1_W[(k+3)*SP + cg];
    }
    #pragma unroll 1
    for (int i = 0; i < 16; ++i) {
      int bb = bq + i*4;
      float acc = 0.f;
      const float4* in4 = (const float4*)&cat[bb*208 + k0];
      #pragma unroll
      for (int k4 = 0; k4 < 25; ++k4) {
        float4 iv = in4[k4];
        acc += iv.x*wreg[k4].x + iv.y*wreg[k4].y + iv.z*wreg[k4].z + iv.w*wreg[k4].w;
      }
      psum[(bb*2 + half)*64 + c] = acc;
    }
    __syncthreads();
    for (int i = tid; i < 4096; i += 512) {
      int bb = i >> 6, cj = i & 63;
      cc_g[bb*256 + blk*64 + cj] =
          psum[(bb*2+0)*64 + cj] + psum[(bb*2+1)*64 + cj] + sp1_b[blk*64 + cj];
    }
  } else {
    // hW (blk 4,5) / q (blk 6,7): 128 cols per block, 100-long dot
    int c = (tid & 63) + 64*((tid >> 6) & 1), bq = tid >> 7;  // bq 0..3
    bool isq = blk >= 6;
    int cg = (blk - (isq ? 6 : 4))*128 + c;
    bool act = cg < H2;
    int cgl = act ? cg : (H2-1);
    const float* Wm = isq ? att_W2 : att_W1;
    float4 wreg[25];
    #pragma unroll
    for (int k4 = 0; k4 < 25; ++k4) {
      int k = k4*4;
      wreg[k4].x = Wm[(k+0)*H2 + cgl];
      wreg[k4].y = Wm[(k+1)*H2 + cgl];
      wreg[k4].z = Wm[(k+2)*H2 + cgl];
      wreg[k4].w = Wm[(k+3)*H2 + cgl];
    }
    #pragma unroll 1
    for (int i = 0; i < 16; ++i) {
      int bb = bq + i*4;
      float acc = 0.f;
      const float4* in4 = (const float4*)&cat[bb*208];
      #pragma unroll
      for (int k4 = 0; k4 < 25; ++k4) {
        float4 iv = in4[k4];
        acc += iv.x*wreg[k4].x + iv.y*wreg[k4].y + iv.z*wreg[k4].z + iv.w*wreg[k4].w;
      }
      if (act) { if (isq) q_g[bb*H2 + cg] = acc; else hW_g[bb*H2 + cg] = acc; }
    }
  }
}

// ---------------- ff1: hid = relu(dec_out @ ff1_W + b) ----
__global__ __launch_bounds__(128) void k_ff1(const float* dec_out, const float* ff1_W,
        const float* ff1_b, float* hid) {
  int row = blockIdx.x, j = threadIdx.x;
  __shared__ __align__(16) float a[104];
  if (j < H) a[j] = dec_out[row*H + j];
  __syncthreads();
  if (j < H) {
    float acc = ff1_b[j];
    const float4* a4 = (const float4*)a;
    #pragma unroll
    for (int k4 = 0; k4 < 25; ++k4) {
      float4 av = a4[k4];
      int k = k4*4;
      acc += av.x*ff1_W[(k+0)*H+j] + av.y*ff1_W[(k+1)*H+j] + av.z*ff1_W[(k+2)*H+j] + av.w*ff1_W[(k+3)*H+j];
    }
    hid[row*H + j] = fmaxf(acc, 0.f);
  }
}

// ---------------- logits GEMM: [2048,100] x [100,20000] (chunked LDS for occupancy) ----
#define KC 20
__global__ __launch_bounds__(256) void k_logits(const float* hid, const float* ff2_W,
        const float* ff2_b, float* out) {
  int bx = blockIdx.x, by = blockIdx.y;
  int tid = threadIdx.x;
  int tx = tid & 15, ty = tid >> 4;
  __shared__ __align__(16) float At[KC*132];
  __shared__ __align__(16) float Wt[KC*132];
  int r0 = by*128;
  int c0 = bx*128;
  float acc[8][8];
  #pragma unroll
  for (int i = 0; i < 8; ++i) {
    #pragma unroll
    for (int j = 0; j < 8; ++j) acc[i][j] = 0.f;
  }
  for (int kc = 0; kc < 100; kc += KC) {
    __syncthreads();
    for (int i = tid; i < 128*KC; i += 256) {
      int r = i & 127, kk = i >> 7;
      At[kk*132 + r] = hid[(r0+r)*H + kc + kk];
    }
    for (int i = tid; i < 128*KC; i += 256) {
      int cidx = i & 127, kk = i >> 7;
      int gc = c0 + cidx;
      Wt[kk*132 + cidx] = (gc < EV) ? ff2_W[(size_t)(kc+kk)*EV + gc] : 0.f;
    }
    __syncthreads();
    #pragma unroll
    for (int kk = 0; kk < KC; ++kk) {
      const float* Ar = At + kk*132;
      const float* Wr = Wt + kk*132;
      float4 a0 = *(const float4*)(Ar + ty*4);
      float4 a1 = *(const float4*)(Ar + 64 + ty*4);
      float4 w0 = *(const float4*)(Wr + tx*4);
      float4 w1 = *(const float4*)(Wr + 64 + tx*4);
      float av[8] = {a0.x,a0.y,a0.z,a0.w,a1.x,a1.y,a1.z,a1.w};
      float wv[8] = {w0.x,w0.y,w0.z,w0.w,w1.x,w1.y,w1.z,w1.w};
      #pragma unroll
      for (int i = 0; i < 8; ++i) {
        #pragma unroll
        for (int j = 0; j < 8; ++j) acc[i][j] += av[i]*wv[j];
      }
    }
  }
  #pragma unroll
  for (int i = 0; i < 8; ++i) {
    int r = r0 + ty*4 + (i < 4 ? i : 60 + i);
    float* orow = out + (size_t)r*EV;
    int ca = c0 + tx*4;
    if (ca < EV) {
      float4 bb = *(const float4*)(ff2_b + ca);
      float4 val = {acc[i][0]+bb.x, acc[i][1]+bb.y, acc[i][2]+bb.z, acc[i][3]+bb.w};
      *(float4*)(orow + ca) = val;
    }
    int cb = c0 + 64 + tx*4;
    if (cb < EV) {
      float4 bb = *(const float4*)(ff2_b + cb);
      float4 val = {acc[i][4]+bb.x, acc[i][5]+bb.y, acc[i][6]+bb.z, acc[i][7]+bb.w};
      *(float4*)(orow + cb) = val;
    }
  }
}

// ---------------- in-place row softmax ----
__global__ __launch_bounds__(256) void k_softmax(float* out) {
  int row = blockIdx.x, tid = threadIdx.x;
  float* p = out + (size_t)row*EV;
  float m = -1e30f, ssum = 0.f;
  for (int j = tid; j < EV; j += 256) {
    float x = p[j];
    if (x > m) { ssum = ssum*expf(m - x) + 1.f; m = x; }
    else ssum += expf(x - m);
  }
  __shared__ float sm[256], ss[256];
  sm[tid] = m; ss[tid] = ssum;
  __syncthreads();
  for (int st = 128; st >= 1; st >>= 1) {
    if (tid < st) {
      float m2 = sm[tid+st], s2 = ss[tid+st];
      float M = fmaxf(sm[tid], m2);
      ss[tid] = ss[tid]*expf(sm[tid]-M) + s2*expf(m2-M);
      sm[tid] = M;
    }
    __syncthreads();
  }
  float M = sm[0];
  float inv = 1.f/ss[0];
  for (int j = tid; j < EV; j += 256) {
    p[j] = expf(p[j] - M) * inv;
  }
}

extern "C" void kernel_launch(void* const* d_in, const int* in_sizes, int n_in,
                              void* d_out, int out_size, void* d_ws, size_t ws_size,
                              hipStream_t stream) {
  (void)in_sizes; (void)n_in; (void)out_size;
  const int*   enc_in  = (const int*)d_in[0];
  const float* femb    = (const float*)d_in[2];
  const float* enc_W   = (const float*)d_in[4];
  const float* enc_U   = (const float*)d_in[5];
  const float* enc_b   = (const float*)d_in[6];
  const float* dec_W   = (const float*)d_in[7];
  const float* dec_U   = (const float*)d_in[8];
  const float* dec_b   = (const float*)d_in[9];
  const float* att_W1  = (const float*)d_in[10];
  const float* att_W2  = (const float*)d_in[11];
  const float* sp1_W   = (const float*)d_in[12];
  const float* sp1_b   = (const float*)d_in[13];
  const float* sp2_W   = (const float*)d_in[14];
  const float* sp2_b   = (const float*)d_in[15];
  const float* ff1_W   = (const float*)d_in[16];
  const float* ff1_b   = (const float*)d_in[17];
  const float* ff2_W   = (const float*)d_in[18];
  const float* ff2_b   = (const float*)d_in[19];
  float* out = (float*)d_out;
  float* ws  = (float*)d_ws;

  float* enc_T  = ws + 0;          // 409600
  float* W_KC   = ws + 409600;     // 45600
  float* hA     = ws + 455200;     // 6400
  float* hB     = ws + 461600;     // 6400
  float* hWb    = ws + 468000;     // 12800
  float* qb     = ws + 480800;     // 12800
  float* rdb    = ws + 493600;     // 6400
  float* ccb    = ws + 500000;     // 16384
  float* OUTb   = ws + 516384;     // 64*1056 = 67584
  float* dec_o  = ws + 583968;     // 204800
  float* hid    = ws + 788768;     // 204800
  float* vbuf   = ws + 993568;     // 256
  float* c2buf  = ws + 993824;     // 32 (pad)
  float* xs_all = ws + 993856;     // 1228800 (dead after k_enc)
  float* P_g    = ws + 993856;     // 4096*456 = 1867776 (aliases xs_all)
  if (ws_size < (size_t)2861632*4) return;   // ~11.5 MB

  k_setup<<<181, 256, 0, stream>>>(att_W1, sp1_W, sp2_W, sp2_b, W_KC, vbuf, c2buf);
  k_embed<<<4096, 320, 0, stream>>>(enc_in, femb, enc_W, enc_b, xs_all);
  k_enc<<<64, 192, 0, stream>>>(enc_U, enc_b, xs_all, enc_T, hA);
  k_initP<<<dim3(4, 64), 512, 0, stream>>>(enc_T, W_KC, P_g);
  k_init_att<<<64, 256, 0, stream>>>(hA, att_W1, att_W2, hWb, qb);
  for (int s = 0; s < TE; ++s) {
    float* h_cur = (s & 1) ? hB : hA;
    float* h_nxt = (s & 1) ? hA : hB;
    k_D1<<<64, 512, 0, stream>>>(s, P_g, enc_T, ccb, OUTb, rdb, hWb, qb, vbuf, c2buf);
    k_D2<<<18, 256, 0, stream>>>(rdb, h_cur, dec_W, dec_U, W_KC, dec_b, OUTb);
    k_D3<<<8, 512, 0, stream>>>(s, OUTb, rdb, h_cur, h_nxt, sp1_W, sp1_b,
                                att_W1, att_W2, ccb, hWb, qb, dec_o);
  }
  k_ff1<<<2048, 128, 0, stream>>>(dec_o, ff1_W, ff1_b, hid);
  k_logits<<<dim3(157, 16), 256, 0, stream>>>(hid, ff2_W, ff2_b, out);
  k_softmax<<<2048, 256, 0, stream>>>(out);
}

// Round 3
// 2183.729 us; speedup vs baseline: 2.0114x; 1.2777x over previous
//
#include <hip/hip_runtime.h>
#include <math.h>

#define B 64
#define TF 64
#define TE 32
#define E_DIM 40
#define H 100
#define H2 200
#define H3 300
#define SP 256
#define EV 20000
#define ROWS (B*TF)        // 4096
#define OC 1312            // OUT cols: xs300 | hs300 | Rsc200 | RY256 | ccrd256

// ---------------- setup: v = rowmean(sp2_W), c2 = mean(sp2_b) ----------------
__global__ __launch_bounds__(256) void k_setup(const float* sp2_W, const float* sp2_b,
                                               float* v, float* c2) {
  if (blockIdx.x == 0) {
    int k = threadIdx.x;
    float s = 0.f;
    for (int j = 0; j < SP; ++j) s += sp2_W[k*SP + j];
    v[k] = s * (1.f/256.f);
  } else if (threadIdx.x == 0) {
    float s = 0.f;
    for (int j = 0; j < SP; ++j) s += sp2_b[j];
    *c2 = s * (1.f/256.f);
  }
}

// ---------------- encoder xs = embed @ enc_W + enc_b[0] ----------------
__global__ __launch_bounds__(320) void k_embed(const int* enc_in, const float* femb,
        const float* enc_W, const float* enc_b, float* xs_all) {
  int row = blockIdx.x;
  int j = threadIdx.x;
  __shared__ __align__(16) float emb[E_DIM];
  int tok = enc_in[row];
  if (j < E_DIM) emb[j] = femb[tok*E_DIM + j];
  __syncthreads();
  if (j < H3) {
    float acc = enc_b[j];
    #pragma unroll
    for (int k = 0; k < E_DIM; ++k) acc += emb[k]*enc_W[k*H3 + j];
    xs_all[row*H3 + j] = acc;
  }
}

// ---------------- encoder GRU recurrence ----------------
__global__ __launch_bounds__(192) void k_enc(const float* __restrict__ enc_U,
        const float* __restrict__ enc_b, const float* __restrict__ xs_all,
        float* __restrict__ enc_T, float* __restrict__ h_state) {
  int b = blockIdx.x, t = threadIdx.x;
  __shared__ __align__(16) float hsh[104];
  __shared__ __align__(16) float hs[304];

  float2 Ur[100];
  float2 bias = {0.f, 0.f};
  if (t < 150) {
    const float* base = enc_U + 2*t;
    #pragma unroll
    for (int k = 0; k < 100; ++k) Ur[k] = *(const float2*)(base + k*H3);
    bias = *(const float2*)(enc_b + H3 + 2*t);
  }
  if (t < H) hsh[t] = 0.f;
  __syncthreads();

  #pragma unroll 1
  for (int step = 0; step < TF; ++step) {
    int row = b*TF + step;
    float xz = 0.f, xr = 0.f, xh = 0.f;
    if (t < H) {
      xz = xs_all[row*H3 + t];
      xr = xs_all[row*H3 + 100 + t];
      xh = xs_all[row*H3 + 200 + t];
    }
    if (t < 150) {
      float a0 = bias.x, a1 = bias.y;
      const float4* h4 = (const float4*)hsh;
      #pragma unroll
      for (int k4 = 0; k4 < 25; ++k4) {
        float4 hv = h4[k4];
        a0 += hv.x*Ur[k4*4+0].x + hv.y*Ur[k4*4+1].x + hv.z*Ur[k4*4+2].x + hv.w*Ur[k4*4+3].x;
        a1 += hv.x*Ur[k4*4+0].y + hv.y*Ur[k4*4+1].y + hv.z*Ur[k4*4+2].y + hv.w*Ur[k4*4+3].y;
      }
      hs[2*t]   = a0;
      hs[2*t+1] = a1;
    }
    __syncthreads();
    if (t < H) {
      float z = 1.f/(1.f+expf(-(xz + hs[t])));
      float r = 1.f/(1.f+expf(-(xr + hs[100+t])));
      float cand = tanhf(xh + r*hs[200+t]);
      float hn = z*hsh[t] + (1.f-z)*cand;
      hsh[t] = hn;
      enc_T[t*ROWS + row] = hn;
    }
    __syncthreads();
  }
  if (t < H) h_state[b*H + t] = hsh[t];
}

// ---------------- sync primitives (agent scope: handles cross-XCD L2) ----------------
__device__ __forceinline__ void sig(unsigned* p) {
  __hip_atomic_fetch_add(p, 1u, __ATOMIC_RELEASE, __HIP_MEMORY_SCOPE_AGENT);
}
__device__ __forceinline__ void wait16(unsigned* p) {
  while (__hip_atomic_load(p, __ATOMIC_ACQUIRE, __HIP_MEMORY_SCOPE_AGENT) < 16u) {
    __builtin_amdgcn_s_sleep(1);
  }
}

// ---------------- persistent decoder: 128 blocks, flag-synced pipeline ----------------
// blocks 0..63  (P1, per batch): P/enc LDS-resident; gate->blend->scores->softmax->rd,
//               plus h-update and h-dependent GEMMs (cc_h, hW, q) with VGPR weights.
// blocks 64..127 (P2, per (bg,cg)): OUT = [rd@dec_W | h@dec_U | rd@W1bot | rd@sp1Wenc |
//               rd@sp1Wmid] with LDS-resident weight slice (hoisted once).
__global__ __launch_bounds__(512, 2) void k_coop(
    const float* __restrict__ enc_T, const float* __restrict__ h_st,
    const float* __restrict__ dec_W, const float* __restrict__ dec_U,
    const float* __restrict__ dec_b,
    const float* __restrict__ sp1_W, const float* __restrict__ sp1_b,
    const float* __restrict__ att_W1, const float* __restrict__ att_W2,
    const float* __restrict__ v_g, const float* __restrict__ c2p,
    float* __restrict__ rd_g, float* __restrict__ h_g,
    float* __restrict__ OUT_g, float* __restrict__ dec_o,
    unsigned* __restrict__ cnt) {
  __shared__ float LD[38464];          // 153856 B union
  int tid = threadIdx.x, blk = blockIdx.x;
  int w = tid >> 6, lane = tid & 63;
  unsigned* C1 = cnt;                  // [32][4]  P1 -> P2
  unsigned* C2 = cnt + 128;            // [32][4]  P2 -> P1
  float c2 = *c2p;

  if (blk < 64) {
    // =========================== P1 role ===========================
    int b = blk, bg = b >> 4;
    float* Psc  = LD;                  // [64][200]
    float* PY   = LD + 12800;          // [64][256]
    float* encL = LD + 29184;          // [100][64]
    float* OUTst= LD + 35584;          // [1312]
    float* hL   = LD + 36896;          // [104]
    float* rdL  = LD + 37000;          // [104]
    float* hWs  = LD + 37104;          // [200]
    float* qs   = LD + 37304;          // [200]
    float* ccs  = LD + 37504;          // [256]
    float* vL   = LD + 37760;          // [256]
    float* spb  = LD + 38016;          // [256]
    float* scor = LD + 38272;          // [64]
    float* alph = LD + 38336;          // [64]
    float* gsh  = LD + 38400;          // [64]

    // ---- hoisted weights (once) ----
    int colA = tid >> 1, halfA = tid & 1;    // cc_h: 2 threads per col, k-split
    float4 wA4[13];                          // 52 ks (half1 pads into rows 100..103, h=0 there)
    #pragma unroll
    for (int i = 0; i < 13; ++i) {
      int k = halfA*52 + i*4;
      wA4[i].x = sp1_W[(k+0)*SP + colA];
      wA4[i].y = sp1_W[(k+1)*SP + colA];
      wA4[i].z = sp1_W[(k+2)*SP + colA];
      wA4[i].w = sp1_W[(k+3)*SP + colA];
    }
    float4 wB4[25];                          // hW (tid<200) / q (200<=tid<400)
    if (tid < 400) {
      const float* Wm = (tid < 200) ? att_W1 : att_W2;
      int cB = (tid < 200) ? tid : tid - 200;
      #pragma unroll
      for (int i = 0; i < 25; ++i) {
        wB4[i].x = Wm[(i*4+0)*H2 + cB];
        wB4[i].y = Wm[(i*4+1)*H2 + cB];
        wB4[i].z = Wm[(i*4+2)*H2 + cB];
        wB4[i].w = Wm[(i*4+3)*H2 + cB];
      }
    }

    // ---- prologue: stage state ----
    for (int i = tid; i < 6400; i += 512)
      encL[i] = enc_T[(i >> 6)*ROWS + b*64 + (i & 63)];
    if (tid < 104) { hL[tid] = (tid < 100) ? h_st[b*100 + tid] : 0.f; rdL[tid] = 0.f; }
    if (tid < 100) h_g[b*100 + tid] = h_st[b*100 + tid];
    if (tid < 256) { vL[tid] = v_g[tid]; spb[tid] = sp1_b[tid]; }
    __syncthreads();

    // ---- P-init: Psc/PY = enc @ [attW1 bottom | sp1W enc-part] ----
    {
      int t = tid >> 3, c8 = tid & 7;
      for (int c = c8; c < 456; c += 8) {
        const float* wp; int ld;
        if (c < 200) { wp = att_W1 + 100*H2 + c; ld = H2; }
        else         { wp = sp1_W + 200*SP + (c-200); ld = SP; }
        float a = 0.f;
        #pragma unroll 4
        for (int k = 0; k < 100; ++k) a += encL[k*64 + t] * wp[k*ld];
        if (c < 200) Psc[t*200 + c] = a; else PY[t*256 + (c-200)] = a;
      }
    }
    // hW/q from h(-1)
    if (tid < 400) {
      float a = 0.f;
      const float4* h4 = (const float4*)hL;
      #pragma unroll
      for (int i = 0; i < 25; ++i) {
        float4 hv = h4[i];
        a += hv.x*wB4[i].x + hv.y*wB4[i].y + hv.z*wB4[i].z + hv.w*wB4[i].w;
      }
      if (tid < 200) hWs[tid] = a; else qs[tid-200] = a;
    }
    __syncthreads();

    #pragma unroll 1
    for (int s = 0; s < TE; ++s) {
      if (s > 0) {
        // wait for OUT(s-1)
        if (tid == 0) wait16(&C2[(s-1)*4 + bg]);
        __syncthreads();
        for (int i = tid; i < OC; i += 512) OUTst[i] = OUT_g[b*OC + i];
        __syncthreads();
        // h-update -> h(s-1)
        if (tid < 100) {
          float xz = OUTst[tid], xr = OUTst[100+tid], xh = OUTst[200+tid];
          float hz = OUTst[300+tid], hr = OUTst[400+tid], hh = OUTst[500+tid];
          float hv = hL[tid];
          float z = 1.f/(1.f+expf(-(xz+hz)));
          float r = 1.f/(1.f+expf(-(xr+hr)));
          float cand = tanhf(xh + r*hh);
          float hn = z*hv + (1.f-z)*cand;
          hL[tid] = hn;
          h_g[b*100 + tid] = hn;
          dec_o[(b*TE + (s-1))*H + tid] = hn;
        }
        __syncthreads();
        // cc_h (k-split pairs) + hW/q from h(s-1)
        {
          float a = 0.f;
          const float4* h4 = (const float4*)(hL + halfA*52);
          #pragma unroll
          for (int i = 0; i < 13; ++i) {
            float4 hv = h4[i];
            a += hv.x*wA4[i].x + hv.y*wA4[i].y + hv.z*wA4[i].z + hv.w*wA4[i].w;
          }
          a += __shfl_xor(a, 1);
          if (halfA == 0) ccs[colA] = a + OUTst[1056 + colA] + spb[colA];
        }
        if (tid < 400) {
          float a = 0.f;
          const float4* h4 = (const float4*)hL;
          #pragma unroll
          for (int i = 0; i < 25; ++i) {
            float4 hv = h4[i];
            a += hv.x*wB4[i].x + hv.y*wB4[i].y + hv.z*wB4[i].z + hv.w*wB4[i].w;
          }
          if (tid < 200) hWs[tid] = a; else qs[tid-200] = a;
        }
        __syncthreads();
        // gate g(s-1) (reads PY pre-blend)
        #pragma unroll
        for (int i = 0; i < 8; ++i) {
          int t = w*8 + i;
          float gp = 0.f;
          #pragma unroll
          for (int jj = 0; jj < 4; ++jj) {
            int j = lane + jj*64;
            gp += fmaxf(ccs[j] + PY[t*256 + j], 0.f) * vL[j];
          }
          #pragma unroll
          for (int mk = 32; mk >= 1; mk >>= 1) gp += __shfl_xor(gp, mk);
          if (lane == 0) gsh[t] = 1.f/(1.f+expf(-(gp + c2)));
        }
        __syncthreads();
        // blend P(s-1), enc(s-1)
        #pragma unroll
        for (int i = 0; i < 8; ++i) {
          int t = w*8 + i;
          float gt = gsh[t], om = 1.f - gt;
          for (int c = lane; c < 200; c += 64)
            Psc[t*200 + c] = gt*Psc[t*200 + c] + om*OUTst[600 + c];
          #pragma unroll
          for (int jj = 0; jj < 4; ++jj) {
            int j = lane + jj*64;
            PY[t*256 + j] = gt*PY[t*256 + j] + om*OUTst[800 + j];
          }
        }
        for (int i = tid; i < 6400; i += 512) {
          int k = i >> 6, t = i & 63;
          float gt = gsh[t];
          encL[i] = gt*encL[i] + (1.f - gt)*rdL[k];
        }
        __syncthreads();
      }
      // scores(s)
      #pragma unroll
      for (int i = 0; i < 8; ++i) {
        int t = w*8 + i;
        float sp = 0.f;
        for (int c = lane; c < 200; c += 64)
          sp += tanhf(hWs[c] + Psc[t*200 + c]) * qs[c];
        #pragma unroll
        for (int mk = 32; mk >= 1; mk >>= 1) sp += __shfl_xor(sp, mk);
        if (lane == 0) scor[t] = sp;
      }
      __syncthreads();
      // softmax
      if (w == 0) {
        float sc = scor[lane];
        float m = sc;
        #pragma unroll
        for (int mk = 32; mk >= 1; mk >>= 1) m = fmaxf(m, __shfl_xor(m, mk));
        float ex = expf(sc - m);
        float ssum = ex;
        #pragma unroll
        for (int mk = 32; mk >= 1; mk >>= 1) ssum += __shfl_xor(ssum, mk);
        alph[lane] = ex / ssum;
      }
      __syncthreads();
      // rd(s)
      float al = alph[lane];
      #pragma unroll
      for (int i = 0; i < 13; ++i) {
        int j = w + i*8;
        if (j < 100) {
          float vs = al * encL[j*64 + lane];
          #pragma unroll
          for (int mk = 32; mk >= 1; mk >>= 1) vs += __shfl_xor(vs, mk);
          if (lane == 0) { rdL[j] = vs; rd_g[b*100 + j] = vs; }
        }
      }
      __syncthreads();
      if (tid == 0) sig(&C1[s*4 + bg]);
    }
    // epilogue: h(31) -> dec_o
    if (tid == 0) wait16(&C2[31*4 + bg]);
    __syncthreads();
    for (int i = tid; i < 600; i += 512) OUTst[i] = OUT_g[b*OC + i];
    __syncthreads();
    if (tid < 100) {
      float xz = OUTst[tid], xr = OUTst[100+tid], xh = OUTst[200+tid];
      float hz = OUTst[300+tid], hr = OUTst[400+tid], hh = OUTst[500+tid];
      float hv = hL[tid];
      float z = 1.f/(1.f+expf(-(xz+hz)));
      float r = 1.f/(1.f+expf(-(xr+hr)));
      float cand = tanhf(xh + r*hh);
      dec_o[(b*TE + 31)*H + tid] = z*hv + (1.f-z)*cand;
    }
  } else {
    // =========================== P2 role ===========================
    int pb = blk - 64;                 // 0..63
    int bg = pb >> 4, cg = pb & 15;
    int c0 = cg*82;
    float* Wt   = LD;                  // [100][84]
    float* rd16 = LD + 8400;           // [16][108]
    float* h16  = LD + 10128;          // [16][108]
    float* bias = LD + 11856;          // [84]

    for (int i = tid; i < 8200; i += 512) {
      int k = i / 82, cc = i - k*82;
      int c = c0 + cc;
      float wv;
      if (c < 300)       wv = dec_W[k*H3 + c];
      else if (c < 600)  wv = dec_U[k*H3 + (c-300)];
      else if (c < 800)  wv = att_W1[(100+k)*H2 + (c-600)];
      else if (c < 1056) wv = sp1_W[(200+k)*SP + (c-800)];
      else               wv = sp1_W[(100+k)*SP + (c-1056)];
      Wt[k*84 + cc] = wv;
    }
    for (int i = tid; i < 84; i += 512) {
      int c = c0 + i;
      bias[i] = (i < 82 && c < 600) ? dec_b[c] : 0.f;
    }

    #pragma unroll 1
    for (int s = 0; s < TE; ++s) {
      if (tid == 0) wait16(&C1[s*4 + bg]);
      __syncthreads();
      for (int i = tid; i < 1600; i += 512) {
        int bb = i / 100, k = i - bb*100;
        rd16[bb*108 + k] = rd_g[(bg*16 + bb)*100 + k];
        h16[bb*108 + k]  = h_g[(bg*16 + bb)*100 + k];
      }
      __syncthreads();
      #pragma unroll
      for (int r = 0; r < 3; ++r) {
        int o = r*512 + tid;
        if (o < 1312) {
          int cc = o >> 4, bb = o & 15;
          int c = c0 + cc;
          const float* in = (c >= 300 && c < 600) ? (h16 + bb*108) : (rd16 + bb*108);
          float a = bias[cc];
          const float4* in4 = (const float4*)in;
          #pragma unroll
          for (int k4 = 0; k4 < 25; ++k4) {
            float4 iv = in4[k4];
            a += iv.x*Wt[(k4*4+0)*84 + cc] + iv.y*Wt[(k4*4+1)*84 + cc]
               + iv.z*Wt[(k4*4+2)*84 + cc] + iv.w*Wt[(k4*4+3)*84 + cc];
          }
          OUT_g[(bg*16 + bb)*OC + c] = a;
        }
      }
      __syncthreads();
      if (tid == 0) sig(&C2[s*4 + bg]);
    }
  }
}

// ---------------- ff1: hid = relu(dec_out @ ff1_W + b) ----------------
__global__ __launch_bounds__(128) void k_ff1(const float* dec_out, const float* ff1_W,
        const float* ff1_b, float* hid) {
  int row = blockIdx.x, j = threadIdx.x;
  __shared__ __align__(16) float a[104];
  if (j < H) a[j] = dec_out[row*H + j];
  __syncthreads();
  if (j < H) {
    float acc = ff1_b[j];
    const float4* a4 = (const float4*)a;
    #pragma unroll
    for (int k4 = 0; k4 < 25; ++k4) {
      float4 av = a4[k4];
      int k = k4*4;
      acc += av.x*ff1_W[(k+0)*H+j] + av.y*ff1_W[(k+1)*H+j] + av.z*ff1_W[(k+2)*H+j] + av.w*ff1_W[(k+3)*H+j];
    }
    hid[row*H + j] = fmaxf(acc, 0.f);
  }
}

// ---------------- logits GEMM: [2048,100] x [100,20000] ----------------
#define KC 20
__global__ __launch_bounds__(256) void k_logits(const float* hid, const float* ff2_W,
        const float* ff2_b, float* out) {
  int bx = blockIdx.x, by = blockIdx.y;
  int tid = threadIdx.x;
  int tx = tid & 15, ty = tid >> 4;
  __shared__ __align__(16) float At[KC*132];
  __shared__ __align__(16) float Wt[KC*132];
  int r0 = by*128;
  int c0 = bx*128;
  float acc[8][8];
  #pragma unroll
  for (int i = 0; i < 8; ++i) {
    #pragma unroll
    for (int j = 0; j < 8; ++j) acc[i][j] = 0.f;
  }
  for (int kc = 0; kc < 100; kc += KC) {
    __syncthreads();
    for (int i = tid; i < 128*KC; i += 256) {
      int r = i & 127, kk = i >> 7;
      At[kk*132 + r] = hid[(r0+r)*H + kc + kk];
    }
    for (int i = tid; i < 128*KC; i += 256) {
      int cidx = i & 127, kk = i >> 7;
      int gc = c0 + cidx;
      Wt[kk*132 + cidx] = (gc < EV) ? ff2_W[(size_t)(kc+kk)*EV + gc] : 0.f;
    }
    __syncthreads();
    #pragma unroll
    for (int kk = 0; kk < KC; ++kk) {
      const float* Ar = At + kk*132;
      const float* Wr = Wt + kk*132;
      float4 a0 = *(const float4*)(Ar + ty*4);
      float4 a1 = *(const float4*)(Ar + 64 + ty*4);
      float4 w0 = *(const float4*)(Wr + tx*4);
      float4 w1 = *(const float4*)(Wr + 64 + tx*4);
      float av[8] = {a0.x,a0.y,a0.z,a0.w,a1.x,a1.y,a1.z,a1.w};
      float wv[8] = {w0.x,w0.y,w0.z,w0.w,w1.x,w1.y,w1.z,w1.w};
      #pragma unroll
      for (int i = 0; i < 8; ++i) {
        #pragma unroll
        for (int j = 0; j < 8; ++j) acc[i][j] += av[i]*wv[j];
      }
    }
  }
  #pragma unroll
  for (int i = 0; i < 8; ++i) {
    int r = r0 + ty*4 + (i < 4 ? i : 60 + i);
    float* orow = out + (size_t)r*EV;
    int ca = c0 + tx*4;
    if (ca < EV) {
      float4 bb = *(const float4*)(ff2_b + ca);
      float4 val = {acc[i][0]+bb.x, acc[i][1]+bb.y, acc[i][2]+bb.z, acc[i][3]+bb.w};
      *(float4*)(orow + ca) = val;
    }
    int cb = c0 + 64 + tx*4;
    if (cb < EV) {
      float4 bb = *(const float4*)(ff2_b + cb);
      float4 val = {acc[i][4]+bb.x, acc[i][5]+bb.y, acc[i][6]+bb.z, acc[i][7]+bb.w};
      *(float4*)(orow + cb) = val;
    }
  }
}

// ---------------- in-place row softmax ----------------
__global__ __launch_bounds__(256) void k_softmax(float* out) {
  int row = blockIdx.x, tid = threadIdx.x;
  float* p = out + (size_t)row*EV;
  float m = -1e30f, ssum = 0.f;
  for (int j = tid; j < EV; j += 256) {
    float x = p[j];
    if (x > m) { ssum = ssum*expf(m - x) + 1.f; m = x; }
    else ssum += expf(x - m);
  }
  __shared__ float sm[256], ss[256];
  sm[tid] = m; ss[tid] = ssum;
  __syncthreads();
  for (int st = 128; st >= 1; st >>= 1) {
    if (tid < st) {
      float m2 = sm[tid+st], s2 = ss[tid+st];
      float M = fmaxf(sm[tid], m2);
      ss[tid] = ss[tid]*expf(sm[tid]-M) + s2*expf(m2-M);
      sm[tid] = M;
    }
    __syncthreads();
  }
  float M = sm[0];
  float inv = 1.f/ss[0];
  for (int j = tid; j < EV; j += 256) {
    p[j] = expf(p[j] - M) * inv;
  }
}

extern "C" void kernel_launch(void* const* d_in, const int* in_sizes, int n_in,
                              void* d_out, int out_size, void* d_ws, size_t ws_size,
                              hipStream_t stream) {
  (void)in_sizes; (void)n_in; (void)out_size;
  const int*   enc_in  = (const int*)d_in[0];
  const float* femb    = (const float*)d_in[2];
  const float* enc_W   = (const float*)d_in[4];
  const float* enc_U   = (const float*)d_in[5];
  const float* enc_b   = (const float*)d_in[6];
  const float* dec_W   = (const float*)d_in[7];
  const float* dec_U   = (const float*)d_in[8];
  const float* dec_b   = (const float*)d_in[9];
  const float* att_W1  = (const float*)d_in[10];
  const float* att_W2  = (const float*)d_in[11];
  const float* sp1_W   = (const float*)d_in[12];
  const float* sp1_b   = (const float*)d_in[13];
  const float* sp2_W   = (const float*)d_in[14];
  const float* sp2_b   = (const float*)d_in[15];
  const float* ff1_W   = (const float*)d_in[16];
  const float* ff1_b   = (const float*)d_in[17];
  const float* ff2_W   = (const float*)d_in[18];
  const float* ff2_b   = (const float*)d_in[19];
  float* out = (float*)d_out;
  float* ws  = (float*)d_ws;

  float* enc_T  = ws + 0;          // 409600
  float* h_st   = ws + 409600;     // 6400
  float* rd_g   = ws + 416000;     // 6400
  float* h_g    = ws + 422400;     // 6400
  float* OUT_g  = ws + 428800;     // 64*1312 = 83968
  float* dec_o  = ws + 512768;     // 204800
  float* hid    = ws + 717568;     // 204800
  float* vbuf   = ws + 922368;     // 256
  float* c2buf  = ws + 922624;     // 32 (pad)
  unsigned* cnt = (unsigned*)(ws + 922656);  // 256 uints
  float* xs_all = ws + 922912;     // 1228800 (dead after k_enc)
  if (ws_size < (size_t)2151712*4) return;   // ~8.6 MB

  k_setup<<<2, 256, 0, stream>>>(sp2_W, sp2_b, vbuf, c2buf);
  k_embed<<<4096, 320, 0, stream>>>(enc_in, femb, enc_W, enc_b, xs_all);
  k_enc<<<64, 192, 0, stream>>>(enc_U, enc_b, xs_all, enc_T, h_st);
  hipMemsetAsync(cnt, 0, 256*sizeof(unsigned), stream);
  k_coop<<<128, 512, 0, stream>>>(enc_T, h_st, dec_W, dec_U, dec_b, sp1_W, sp1_b,
                                  att_W1, att_W2, vbuf, c2buf,
                                  rd_g, h_g, OUT_g, dec_o, cnt);
  k_ff1<<<2048, 128, 0, stream>>>(dec_o, ff1_W, ff1_b, hid);
  k_logits<<<dim3(157, 16), 256, 0, stream>>>(hid, ff2_W, ff2_b, out);
  k_softmax<<<2048, 256, 0, stream>>>(out);
}

// Round 4
// 1726.156 us; speedup vs baseline: 2.5446x; 1.2651x over previous
//
#include <hip/hip_runtime.h>
#include <math.h>

#define B 64
#define TF 64
#define TE 32
#define E_DIM 40
#define H 100
#define H2 200
#define H3 300
#define SP 256
#define EV 20000
#define ROWS (B*TF)        // 4096
#define OC 1312            // OUT cols: xs300 | hs300 | Rsc200 | RY256 | ccrd256

// ---------------- setup: v = rowmean(sp2_W), c2 = mean(sp2_b) ----------------
__global__ __launch_bounds__(256) void k_setup(const float* sp2_W, const float* sp2_b,
                                               float* v, float* c2) {
  if (blockIdx.x == 0) {
    int k = threadIdx.x;
    float s = 0.f;
    for (int j = 0; j < SP; ++j) s += sp2_W[k*SP + j];
    v[k] = s * (1.f/256.f);
  } else if (threadIdx.x == 0) {
    float s = 0.f;
    for (int j = 0; j < SP; ++j) s += sp2_b[j];
    *c2 = s * (1.f/256.f);
  }
}

// ---------------- encoder xs = embed @ enc_W + enc_b[0] ----------------
__global__ __launch_bounds__(320) void k_embed(const int* enc_in, const float* femb,
        const float* enc_W, const float* enc_b, float* xs_all) {
  int row = blockIdx.x;
  int j = threadIdx.x;
  __shared__ __align__(16) float emb[E_DIM];
  int tok = enc_in[row];
  if (j < E_DIM) emb[j] = femb[tok*E_DIM + j];
  __syncthreads();
  if (j < H3) {
    float acc = enc_b[j];
    #pragma unroll
    for (int k = 0; k < E_DIM; ++k) acc += emb[k]*enc_W[k*H3 + j];
    xs_all[row*H3 + j] = acc;
  }
}

// ---------------- encoder GRU recurrence ----------------
__global__ __launch_bounds__(192) void k_enc(const float* __restrict__ enc_U,
        const float* __restrict__ enc_b, const float* __restrict__ xs_all,
        float* __restrict__ enc_T, float* __restrict__ h_state) {
  int b = blockIdx.x, t = threadIdx.x;
  __shared__ __align__(16) float hsh[104];
  __shared__ __align__(16) float hs[304];

  float2 Ur[100];
  float2 bias = {0.f, 0.f};
  if (t < 150) {
    const float* base = enc_U + 2*t;
    #pragma unroll
    for (int k = 0; k < 100; ++k) Ur[k] = *(const float2*)(base + k*H3);
    bias = *(const float2*)(enc_b + H3 + 2*t);
  }
  if (t < H) hsh[t] = 0.f;
  __syncthreads();

  #pragma unroll 1
  for (int step = 0; step < TF; ++step) {
    int row = b*TF + step;
    float xz = 0.f, xr = 0.f, xh = 0.f;
    if (t < H) {
      xz = xs_all[row*H3 + t];
      xr = xs_all[row*H3 + 100 + t];
      xh = xs_all[row*H3 + 200 + t];
    }
    if (t < 150) {
      float a0 = bias.x, a1 = bias.y;
      const float4* h4 = (const float4*)hsh;
      #pragma unroll
      for (int k4 = 0; k4 < 25; ++k4) {
        float4 hv = h4[k4];
        a0 += hv.x*Ur[k4*4+0].x + hv.y*Ur[k4*4+1].x + hv.z*Ur[k4*4+2].x + hv.w*Ur[k4*4+3].x;
        a1 += hv.x*Ur[k4*4+0].y + hv.y*Ur[k4*4+1].y + hv.z*Ur[k4*4+2].y + hv.w*Ur[k4*4+3].y;
      }
      hs[2*t]   = a0;
      hs[2*t+1] = a1;
    }
    __syncthreads();
    if (t < H) {
      float z = 1.f/(1.f+expf(-(xz + hs[t])));
      float r = 1.f/(1.f+expf(-(xr + hs[100+t])));
      float cand = tanhf(xh + r*hs[200+t]);
      float hn = z*hsh[t] + (1.f-z)*cand;
      hsh[t] = hn;
      enc_T[t*ROWS + row] = hn;
    }
    __syncthreads();
  }
  if (t < H) h_state[b*H + t] = hsh[t];
}

// ---------------- sync primitives ----------------
// signal: release fetch_add (one L2 writeback per signal — covers the block's stores
//         since all waves share the CU/XCD L2 and __syncthreads drained vmcnt).
// wait:   RELAXED polling (coherent at MALL, NO per-poll cache invalidate), then a
//         single acquire fence. Per-poll ACQUIRE loads emit buffer_inv each
//         iteration -> L2-invalidate storm (round-3 failure: 53 us/step).
__device__ __forceinline__ void sig(unsigned* p) {
  __hip_atomic_fetch_add(p, 1u, __ATOMIC_RELEASE, __HIP_MEMORY_SCOPE_AGENT);
}
__device__ __forceinline__ void wait16(unsigned* p) {
  while (__hip_atomic_load(p, __ATOMIC_RELAXED, __HIP_MEMORY_SCOPE_AGENT) < 16u) {
    __builtin_amdgcn_s_sleep(1);
  }
  __builtin_amdgcn_fence(__ATOMIC_ACQUIRE, "agent");
}

// ---------------- persistent decoder: 128 blocks, flag-synced pipeline ----------------
__global__ __launch_bounds__(512, 2) void k_coop(
    const float* __restrict__ enc_T, const float* __restrict__ h_st,
    const float* __restrict__ dec_W, const float* __restrict__ dec_U,
    const float* __restrict__ dec_b,
    const float* __restrict__ sp1_W, const float* __restrict__ sp1_b,
    const float* __restrict__ att_W1, const float* __restrict__ att_W2,
    const float* __restrict__ v_g, const float* __restrict__ c2p,
    float* __restrict__ rd_g, float* __restrict__ h_g,
    float* __restrict__ OUT_g, float* __restrict__ dec_o,
    unsigned* __restrict__ cnt) {
  __shared__ float LD[38464];          // 153856 B union
  int tid = threadIdx.x, blk = blockIdx.x;
  int w = tid >> 6, lane = tid & 63;
  unsigned* C1 = cnt;                  // [32][4]  P1 -> P2
  unsigned* C2 = cnt + 128;            // [32][4]  P2 -> P1
  float c2 = *c2p;

  if (blk < 64) {
    // =========================== P1 role ===========================
    int b = blk, bg = b >> 4;
    float* Psc  = LD;                  // [64][200]
    float* PY   = LD + 12800;          // [64][256]
    float* encL = LD + 29184;          // [100][64]
    float* OUTst= LD + 35584;          // [1312]
    float* hL   = LD + 36896;          // [104]
    float* rdL  = LD + 37000;          // [104]
    float* hWs  = LD + 37104;          // [200]
    float* qs   = LD + 37304;          // [200]
    float* ccs  = LD + 37504;          // [256]
    float* vL   = LD + 37760;          // [256]
    float* spb  = LD + 38016;          // [256]
    float* scor = LD + 38272;          // [64]
    float* alph = LD + 38336;          // [64]
    float* gsh  = LD + 38400;          // [64]

    // ---- hoisted weights (once) ----
    int colA = tid >> 1, halfA = tid & 1;    // cc_h: 2 threads per col, k-split
    float4 wA4[13];
    #pragma unroll
    for (int i = 0; i < 13; ++i) {
      int k = halfA*52 + i*4;
      wA4[i].x = sp1_W[(k+0)*SP + colA];
      wA4[i].y = sp1_W[(k+1)*SP + colA];
      wA4[i].z = sp1_W[(k+2)*SP + colA];
      wA4[i].w = sp1_W[(k+3)*SP + colA];
    }
    float4 wB4[25];                          // hW (tid<200) / q (200<=tid<400)
    if (tid < 400) {
      const float* Wm = (tid < 200) ? att_W1 : att_W2;
      int cB = (tid < 200) ? tid : tid - 200;
      #pragma unroll
      for (int i = 0; i < 25; ++i) {
        wB4[i].x = Wm[(i*4+0)*H2 + cB];
        wB4[i].y = Wm[(i*4+1)*H2 + cB];
        wB4[i].z = Wm[(i*4+2)*H2 + cB];
        wB4[i].w = Wm[(i*4+3)*H2 + cB];
      }
    }

    // ---- prologue: stage state ----
    for (int i = tid; i < 6400; i += 512)
      encL[i] = enc_T[(i >> 6)*ROWS + b*64 + (i & 63)];
    if (tid < 104) { hL[tid] = (tid < 100) ? h_st[b*100 + tid] : 0.f; rdL[tid] = 0.f; }
    if (tid < 100) h_g[b*100 + tid] = h_st[b*100 + tid];
    if (tid < 256) { vL[tid] = v_g[tid]; spb[tid] = sp1_b[tid]; }
    __syncthreads();

    // ---- P-init: Psc/PY = enc @ [attW1 bottom | sp1W enc-part] ----
    {
      int t = tid >> 3, c8 = tid & 7;
      for (int c = c8; c < 456; c += 8) {
        const float* wp; int ld;
        if (c < 200) { wp = att_W1 + 100*H2 + c; ld = H2; }
        else         { wp = sp1_W + 200*SP + (c-200); ld = SP; }
        float a = 0.f;
        #pragma unroll 4
        for (int k = 0; k < 100; ++k) a += encL[k*64 + t] * wp[k*ld];
        if (c < 200) Psc[t*200 + c] = a; else PY[t*256 + (c-200)] = a;
      }
    }
    // hW/q from h(-1)
    if (tid < 400) {
      float a = 0.f;
      const float4* h4 = (const float4*)hL;
      #pragma unroll
      for (int i = 0; i < 25; ++i) {
        float4 hv = h4[i];
        a += hv.x*wB4[i].x + hv.y*wB4[i].y + hv.z*wB4[i].z + hv.w*wB4[i].w;
      }
      if (tid < 200) hWs[tid] = a; else qs[tid-200] = a;
    }
    __syncthreads();

    #pragma unroll 1
    for (int s = 0; s < TE; ++s) {
      if (s > 0) {
        // wait for OUT(s-1)
        if (tid == 0) wait16(&C2[(s-1)*4 + bg]);
        __syncthreads();
        for (int i = tid; i < OC; i += 512) OUTst[i] = OUT_g[b*OC + i];
        __syncthreads();
        // h-update -> h(s-1)
        if (tid < 100) {
          float xz = OUTst[tid], xr = OUTst[100+tid], xh = OUTst[200+tid];
          float hz = OUTst[300+tid], hr = OUTst[400+tid], hh = OUTst[500+tid];
          float hv = hL[tid];
          float z = 1.f/(1.f+expf(-(xz+hz)));
          float r = 1.f/(1.f+expf(-(xr+hr)));
          float cand = tanhf(xh + r*hh);
          float hn = z*hv + (1.f-z)*cand;
          hL[tid] = hn;
          h_g[b*100 + tid] = hn;
          dec_o[(b*TE + (s-1))*H + tid] = hn;
        }
        __syncthreads();
        // cc_h (k-split pairs) + hW/q from h(s-1)
        {
          float a = 0.f;
          const float4* h4 = (const float4*)(hL + halfA*52);
          #pragma unroll
          for (int i = 0; i < 13; ++i) {
            float4 hv = h4[i];
            a += hv.x*wA4[i].x + hv.y*wA4[i].y + hv.z*wA4[i].z + hv.w*wA4[i].w;
          }
          a += __shfl_xor(a, 1);
          if (halfA == 0) ccs[colA] = a + OUTst[1056 + colA] + spb[colA];
        }
        if (tid < 400) {
          float a = 0.f;
          const float4* h4 = (const float4*)hL;
          #pragma unroll
          for (int i = 0; i < 25; ++i) {
            float4 hv = h4[i];
            a += hv.x*wB4[i].x + hv.y*wB4[i].y + hv.z*wB4[i].z + hv.w*wB4[i].w;
          }
          if (tid < 200) hWs[tid] = a; else qs[tid-200] = a;
        }
        __syncthreads();
        // gate g(s-1) (reads PY pre-blend)
        #pragma unroll
        for (int i = 0; i < 8; ++i) {
          int t = w*8 + i;
          float gp = 0.f;
          #pragma unroll
          for (int jj = 0; jj < 4; ++jj) {
            int j = lane + jj*64;
            gp += fmaxf(ccs[j] + PY[t*256 + j], 0.f) * vL[j];
          }
          #pragma unroll
          for (int mk = 32; mk >= 1; mk >>= 1) gp += __shfl_xor(gp, mk);
          if (lane == 0) gsh[t] = 1.f/(1.f+expf(-(gp + c2)));
        }
        __syncthreads();
        // blend PY + enc, and FUSED Psc-blend + scores(s)
        #pragma unroll
        for (int i = 0; i < 8; ++i) {
          int t = w*8 + i;
          float gt = gsh[t], om = 1.f - gt;
          #pragma unroll
          for (int jj = 0; jj < 4; ++jj) {
            int j = lane + jj*64;
            PY[t*256 + j] = gt*PY[t*256 + j] + om*OUTst[800 + j];
          }
        }
        for (int i = tid; i < 6400; i += 512) {
          int k = i >> 6, t = i & 63;
          float gt = gsh[t];
          encL[i] = gt*encL[i] + (1.f - gt)*rdL[k];
        }
        #pragma unroll
        for (int i = 0; i < 8; ++i) {
          int t = w*8 + i;
          float gt = gsh[t], om = 1.f - gt;
          float sp = 0.f;
          for (int c = lane; c < 200; c += 64) {
            float nv = gt*Psc[t*200 + c] + om*OUTst[600 + c];
            Psc[t*200 + c] = nv;
            sp += tanhf(hWs[c] + nv) * qs[c];
          }
          #pragma unroll
          for (int mk = 32; mk >= 1; mk >>= 1) sp += __shfl_xor(sp, mk);
          if (lane == 0) scor[t] = sp;
        }
        __syncthreads();
      } else {
        // scores(0) on fresh Psc
        #pragma unroll
        for (int i = 0; i < 8; ++i) {
          int t = w*8 + i;
          float sp = 0.f;
          for (int c = lane; c < 200; c += 64)
            sp += tanhf(hWs[c] + Psc[t*200 + c]) * qs[c];
          #pragma unroll
          for (int mk = 32; mk >= 1; mk >>= 1) sp += __shfl_xor(sp, mk);
          if (lane == 0) scor[t] = sp;
        }
        __syncthreads();
      }
      // softmax
      if (w == 0) {
        float sc = scor[lane];
        float m = sc;
        #pragma unroll
        for (int mk = 32; mk >= 1; mk >>= 1) m = fmaxf(m, __shfl_xor(m, mk));
        float ex = expf(sc - m);
        float ssum = ex;
        #pragma unroll
        for (int mk = 32; mk >= 1; mk >>= 1) ssum += __shfl_xor(ssum, mk);
        alph[lane] = ex / ssum;
      }
      __syncthreads();
      // rd(s)
      float al = alph[lane];
      #pragma unroll
      for (int i = 0; i < 13; ++i) {
        int j = w + i*8;
        if (j < 100) {
          float vs = al * encL[j*64 + lane];
          #pragma unroll
          for (int mk = 32; mk >= 1; mk >>= 1) vs += __shfl_xor(vs, mk);
          if (lane == 0) { rdL[j] = vs; rd_g[b*100 + j] = vs; }
        }
      }
      __syncthreads();
      if (tid == 0) sig(&C1[s*4 + bg]);
    }
    // epilogue: h(31) -> dec_o
    if (tid == 0) wait16(&C2[31*4 + bg]);
    __syncthreads();
    for (int i = tid; i < 600; i += 512) OUTst[i] = OUT_g[b*OC + i];
    __syncthreads();
    if (tid < 100) {
      float xz = OUTst[tid], xr = OUTst[100+tid], xh = OUTst[200+tid];
      float hz = OUTst[300+tid], hr = OUTst[400+tid], hh = OUTst[500+tid];
      float hv = hL[tid];
      float z = 1.f/(1.f+expf(-(xz+hz)));
      float r = 1.f/(1.f+expf(-(xr+hr)));
      float cand = tanhf(xh + r*hh);
      dec_o[(b*TE + 31)*H + tid] = z*hv + (1.f-z)*cand;
    }
  } else {
    // =========================== P2 role ===========================
    int pb = blk - 64;                 // 0..63
    int bg = pb >> 4, cg = pb & 15;
    int c0 = cg*82;
    float* Wt   = LD;                  // [100][84]
    float* rd16 = LD + 8400;           // [16][108]
    float* h16  = LD + 10128;          // [16][108]
    float* bias = LD + 11856;          // [84]

    for (int i = tid; i < 8200; i += 512) {
      int k = i / 82, cc = i - k*82;
      int c = c0 + cc;
      float wv;
      if (c < 300)       wv = dec_W[k*H3 + c];
      else if (c < 600)  wv = dec_U[k*H3 + (c-300)];
      else if (c < 800)  wv = att_W1[(100+k)*H2 + (c-600)];
      else if (c < 1056) wv = sp1_W[(200+k)*SP + (c-800)];
      else               wv = sp1_W[(100+k)*SP + (c-1056)];
      Wt[k*84 + cc] = wv;
    }
    for (int i = tid; i < 84; i += 512) {
      int c = c0 + i;
      bias[i] = (i < 82 && c < 600) ? dec_b[c] : 0.f;
    }

    #pragma unroll 1
    for (int s = 0; s < TE; ++s) {
      if (tid == 0) wait16(&C1[s*4 + bg]);
      __syncthreads();
      for (int i = tid; i < 1600; i += 512) {
        int bb = i / 100, k = i - bb*100;
        rd16[bb*108 + k] = rd_g[(bg*16 + bb)*100 + k];
        h16[bb*108 + k]  = h_g[(bg*16 + bb)*100 + k];
      }
      __syncthreads();
      #pragma unroll
      for (int r = 0; r < 3; ++r) {
        int o = r*512 + tid;
        if (o < 1312) {
          int cc = o >> 4, bb = o & 15;
          int c = c0 + cc;
          const float* in = (c >= 300 && c < 600) ? (h16 + bb*108) : (rd16 + bb*108);
          float a = bias[cc];
          const float4* in4 = (const float4*)in;
          #pragma unroll
          for (int k4 = 0; k4 < 25; ++k4) {
            float4 iv = in4[k4];
            a += iv.x*Wt[(k4*4+0)*84 + cc] + iv.y*Wt[(k4*4+1)*84 + cc]
               + iv.z*Wt[(k4*4+2)*84 + cc] + iv.w*Wt[(k4*4+3)*84 + cc];
          }
          OUT_g[(bg*16 + bb)*OC + c] = a;
        }
      }
      __syncthreads();
      if (tid == 0) sig(&C2[s*4 + bg]);
    }
  }
}

// ---------------- ff1: hid = relu(dec_out @ ff1_W + b) ----------------
__global__ __launch_bounds__(128) void k_ff1(const float* dec_out, const float* ff1_W,
        const float* ff1_b, float* hid) {
  int row = blockIdx.x, j = threadIdx.x;
  __shared__ __align__(16) float a[104];
  if (j < H) a[j] = dec_out[row*H + j];
  __syncthreads();
  if (j < H) {
    float acc = ff1_b[j];
    const float4* a4 = (const float4*)a;
    #pragma unroll
    for (int k4 = 0; k4 < 25; ++k4) {
      float4 av = a4[k4];
      int k = k4*4;
      acc += av.x*ff1_W[(k+0)*H+j] + av.y*ff1_W[(k+1)*H+j] + av.z*ff1_W[(k+2)*H+j] + av.w*ff1_W[(k+3)*H+j];
    }
    hid[row*H + j] = fmaxf(acc, 0.f);
  }
}

// ---------------- logits GEMM: [2048,100] x [100,20000] ----------------
#define KC 20
__global__ __launch_bounds__(256) void k_logits(const float* hid, const float* ff2_W,
        const float* ff2_b, float* out) {
  int bx = blockIdx.x, by = blockIdx.y;
  int tid = threadIdx.x;
  int tx = tid & 15, ty = tid >> 4;
  __shared__ __align__(16) float At[KC*132];
  __shared__ __align__(16) float Wt[KC*132];
  int r0 = by*128;
  int c0 = bx*128;
  float acc[8][8];
  #pragma unroll
  for (int i = 0; i < 8; ++i) {
    #pragma unroll
    for (int j = 0; j < 8; ++j) acc[i][j] = 0.f;
  }
  for (int kc = 0; kc < 100; kc += KC) {
    __syncthreads();
    for (int i = tid; i < 128*KC; i += 256) {
      int r = i & 127, kk = i >> 7;
      At[kk*132 + r] = hid[(r0+r)*H + kc + kk];
    }
    for (int i = tid; i < 128*KC; i += 256) {
      int cidx = i & 127, kk = i >> 7;
      int gc = c0 + cidx;
      Wt[kk*132 + cidx] = (gc < EV) ? ff2_W[(size_t)(kc+kk)*EV + gc] : 0.f;
    }
    __syncthreads();
    #pragma unroll
    for (int kk = 0; kk < KC; ++kk) {
      const float* Ar = At + kk*132;
      const float* Wr = Wt + kk*132;
      float4 a0 = *(const float4*)(Ar + ty*4);
      float4 a1 = *(const float4*)(Ar + 64 + ty*4);
      float4 w0 = *(const float4*)(Wr + tx*4);
      float4 w1 = *(const float4*)(Wr + 64 + tx*4);
      float av[8] = {a0.x,a0.y,a0.z,a0.w,a1.x,a1.y,a1.z,a1.w};
      float wv[8] = {w0.x,w0.y,w0.z,w0.w,w1.x,w1.y,w1.z,w1.w};
      #pragma unroll
      for (int i = 0; i < 8; ++i) {
        #pragma unroll
        for (int j = 0; j < 8; ++j) acc[i][j] += av[i]*wv[j];
      }
    }
  }
  #pragma unroll
  for (int i = 0; i < 8; ++i) {
    int r = r0 + ty*4 + (i < 4 ? i : 60 + i);
    float* orow = out + (size_t)r*EV;
    int ca = c0 + tx*4;
    if (ca < EV) {
      float4 bb = *(const float4*)(ff2_b + ca);
      float4 val = {acc[i][0]+bb.x, acc[i][1]+bb.y, acc[i][2]+bb.z, acc[i][3]+bb.w};
      *(float4*)(orow + ca) = val;
    }
    int cb = c0 + 64 + tx*4;
    if (cb < EV) {
      float4 bb = *(const float4*)(ff2_b + cb);
      float4 val = {acc[i][4]+bb.x, acc[i][5]+bb.y, acc[i][6]+bb.z, acc[i][7]+bb.w};
      *(float4*)(orow + cb) = val;
    }
  }
}

// ---------------- in-place row softmax ----------------
__global__ __launch_bounds__(256) void k_softmax(float* out) {
  int row = blockIdx.x, tid = threadIdx.x;
  float* p = out + (size_t)row*EV;
  float m = -1e30f, ssum = 0.f;
  for (int j = tid; j < EV; j += 256) {
    float x = p[j];
    if (x > m) { ssum = ssum*expf(m - x) + 1.f; m = x; }
    else ssum += expf(x - m);
  }
  __shared__ float sm[256], ss[256];
  sm[tid] = m; ss[tid] = ssum;
  __syncthreads();
  for (int st = 128; st >= 1; st >>= 1) {
    if (tid < st) {
      float m2 = sm[tid+st], s2 = ss[tid+st];
      float M = fmaxf(sm[tid], m2);
      ss[tid] = ss[tid]*expf(sm[tid]-M) + s2*expf(m2-M);
      sm[tid] = M;
    }
    __syncthreads();
  }
  float M = sm[0];
  float inv = 1.f/ss[0];
  for (int j = tid; j < EV; j += 256) {
    p[j] = expf(p[j] - M) * inv;
  }
}

extern "C" void kernel_launch(void* const* d_in, const int* in_sizes, int n_in,
                              void* d_out, int out_size, void* d_ws, size_t ws_size,
                              hipStream_t stream) {
  (void)in_sizes; (void)n_in; (void)out_size;
  const int*   enc_in  = (const int*)d_in[0];
  const float* femb    = (const float*)d_in[2];
  const float* enc_W   = (const float*)d_in[4];
  const float* enc_U   = (const float*)d_in[5];
  const float* enc_b   = (const float*)d_in[6];
  const float* dec_W   = (const float*)d_in[7];
  const float* dec_U   = (const float*)d_in[8];
  const float* dec_b   = (const float*)d_in[9];
  const float* att_W1  = (const float*)d_in[10];
  const float* att_W2  = (const float*)d_in[11];
  const float* sp1_W   = (const float*)d_in[12];
  const float* sp1_b   = (const float*)d_in[13];
  const float* sp2_W   = (const float*)d_in[14];
  const float* sp2_b   = (const float*)d_in[15];
  const float* ff1_W   = (const float*)d_in[16];
  const float* ff1_b   = (const float*)d_in[17];
  const float* ff2_W   = (const float*)d_in[18];
  const float* ff2_b   = (const float*)d_in[19];
  float* out = (float*)d_out;
  float* ws  = (float*)d_ws;

  float* enc_T  = ws + 0;          // 409600
  float* h_st   = ws + 409600;     // 6400
  float* rd_g   = ws + 416000;     // 6400
  float* h_g    = ws + 422400;     // 6400
  float* OUT_g  = ws + 428800;     // 64*1312 = 83968
  float* dec_o  = ws + 512768;     // 204800
  float* hid    = ws + 717568;     // 204800
  float* vbuf   = ws + 922368;     // 256
  float* c2buf  = ws + 922624;     // 32 (pad)
  unsigned* cnt = (unsigned*)(ws + 922656);  // 256 uints
  float* xs_all = ws + 922912;     // 1228800 (dead after k_enc)
  if (ws_size < (size_t)2151712*4) return;   // ~8.6 MB

  k_setup<<<2, 256, 0, stream>>>(sp2_W, sp2_b, vbuf, c2buf);
  k_embed<<<4096, 320, 0, stream>>>(enc_in, femb, enc_W, enc_b, xs_all);
  k_enc<<<64, 192, 0, stream>>>(enc_U, enc_b, xs_all, enc_T, h_st);
  hipMemsetAsync(cnt, 0, 256*sizeof(unsigned), stream);
  k_coop<<<128, 512, 0, stream>>>(enc_T, h_st, dec_W, dec_U, dec_b, sp1_W, sp1_b,
                                  att_W1, att_W2, vbuf, c2buf,
                                  rd_g, h_g, OUT_g, dec_o, cnt);
  k_ff1<<<2048, 128, 0, stream>>>(dec_o, ff1_W, ff1_b, hid);
  k_logits<<<dim3(157, 16), 256, 0, stream>>>(hid, ff2_W, ff2_b, out);
  k_softmax<<<2048, 256, 0, stream>>>(out);
}